// Round 6
// baseline (714.070 us; speedup 1.0000x reference)
//
#include <hip/hip_runtime.h>
#include <cmath>

#define NH 4
#define NG 128

typedef _Float16 half8 __attribute__((ext_vector_type(8)));
typedef _Float16 half4v __attribute__((ext_vector_type(4)));
typedef _Float16 half2v __attribute__((ext_vector_type(2)));
typedef float f32x4 __attribute__((ext_vector_type(4)));

#if defined(__has_builtin)
# if __has_builtin(__builtin_amdgcn_fdot2)
#  define USE_FDOT2 1
# endif
# if __has_builtin(__builtin_amdgcn_update_dpp)
#  define USE_DPP 1
# endif
#endif

__device__ inline float vload(const float* p) { return *(volatile const float*)p; }

// sum over each aligned 8-lane group, all lanes get result
__device__ inline float dpp_sum8(float p) {
#ifdef USE_DPP
    int pi = __builtin_bit_cast(int, p);
    int a = __builtin_amdgcn_update_dpp(0, pi, 0xB1, 0xF, 0xF, true);   // quad_perm [1,0,3,2]
    p += __builtin_bit_cast(float, a);
    pi = __builtin_bit_cast(int, p);
    a = __builtin_amdgcn_update_dpp(0, pi, 0x4E, 0xF, 0xF, true);       // quad_perm [2,3,0,1]
    p += __builtin_bit_cast(float, a);
    pi = __builtin_bit_cast(int, p);
    a = __builtin_amdgcn_update_dpp(0, pi, 0x141, 0xF, 0xF, true);      // row_half_mirror
    p += __builtin_bit_cast(float, a);
    return p;
#else
    p += __shfl_xor(p, 1); p += __shfl_xor(p, 2); p += __shfl_xor(p, 4);
    return p;
#endif
}

// ---------------- CSR build: hist + graph bounds in one dispatch ----------------

__global__ void __launch_bounds__(256) hb_kernel(const int* __restrict__ dst,
                                                 int* __restrict__ deg,
                                                 const int* __restrict__ gid,
                                                 int* __restrict__ gstart, int N, int E) {
    int i = blockIdx.x * 256 + threadIdx.x;
    if (i < E) atomicAdd(&deg[dst[i]], 1);
    if (i < N) {
        int a = gid[i];
        if (i == 0)
            for (int g = 0; g <= a; g++) gstart[g] = 0;
        int b = (i + 1 < N) ? gid[i + 1] : NG;
        for (int g = a + 1; g <= b && g < NG; g++) gstart[g] = i + 1;
    }
}

// single-dispatch row offsets: per-block scan + atomic base (regions unordered, deg[] kept)
__global__ void __launch_bounds__(256) rowptr_kernel(const int* __restrict__ deg,
                                                     int* __restrict__ row_ptr,
                                                     int* __restrict__ gbase,
                                                     const int* __restrict__ gstart,
                                                     int* __restrict__ cntg, int N) {
    __shared__ int red[256];
    __shared__ int base_s;
    int t = threadIdx.x;
    int base = blockIdx.x * 1024 + t * 4;
    int d[4];
    int s = 0;
#pragma unroll
    for (int j = 0; j < 4; j++) {
        int i = base + j;
        d[j] = (i < N) ? deg[i] : 0;
        s += d[j];
    }
    red[t] = s;
    __syncthreads();
    for (int off = 1; off < 256; off <<= 1) {
        int v = (t >= off) ? red[t - off] : 0;
        __syncthreads();
        red[t] += v;
        __syncthreads();
    }
    if (t == 255) base_s = atomicAdd(gbase, red[255]);
    __syncthreads();
    int excl = red[t] - s + base_s;
#pragma unroll
    for (int j = 0; j < 4; j++) {
        int i = base + j;
        if (i < N) row_ptr[i] = excl;
        excl += d[j];
    }
    if (blockIdx.x == 0 && t < NG) {
        int s1 = (t == NG - 1) ? N : gstart[t + 1];
        cntg[t] = s1 - gstart[t];
    }
}

__global__ void __launch_bounds__(256) scatter_kernel(const int* __restrict__ src,
                                                      const int* __restrict__ dst,
                                                      const int* __restrict__ row_ptr,
                                                      int* __restrict__ cursor,
                                                      int* __restrict__ col_src, int E) {
    int e = blockIdx.x * 256 + threadIdx.x;
    if (e < E) {
        int d = dst[e];
        int pos = row_ptr[d] + atomicAdd(&cursor[d], 1);
        col_src[pos] = src[e];
    }
}

// ------- one-time: W -> Wt[c][k] f16; attn -> f16; init bnA/bnB -------

__global__ void __launch_bounds__(256) wcvt_kernel(
    const float* __restrict__ Wsrc, const float* __restrict__ Wdst,
    const float* __restrict__ attn,
    _Float16* __restrict__ Wt, _Float16* __restrict__ att16,
    float* bnA, float* bnB)
{
    __shared__ _Float16 lt[256 * 66];
    int b = blockIdx.x;                         // b = l*2 + m
    const float* W = (b & 1) ? (Wdst + (size_t)(b >> 1) * 16384)
                             : (Wsrc + (size_t)(b >> 1) * 16384);
    _Float16* o = Wt + (size_t)b * 16384;
    int t = threadIdx.x;
    for (int i = t; i < 16384; i += 256) {
        int k = i >> 8, c = i & 255;
        lt[c * 66 + k] = (_Float16)W[i];
    }
    __syncthreads();
    for (int i = t; i < 16384; i += 256) {
        int c = i >> 6, k = i & 63;
        o[i] = lt[c * 66 + k];
    }
    if (b == 0) {
        if (t < 64) { bnA[t] = 1.f; bnB[t] = 0.f; }
        for (int i = t; i < 3 * 256; i += 256) att16[i] = (_Float16)attn[i];
    }
}

// ---------------- fused BN-affine + dual GEMM (f16 MFMA), fs+fd in one block ----------
// 512 threads = 8 waves; wave w: y=w>>2 (0=fs,1=fd), cols (w&3)*64.

__global__ void __launch_bounds__(512) gemm_kernel(
    const float* __restrict__ h, const float* __restrict__ bnA, const float* __restrict__ bnB,
    const _Float16* __restrict__ Wt,            // [2][256][64] f16 for this layer
    const float* __restrict__ bsrc, const float* __restrict__ bdst,
    _Float16* __restrict__ fsh, _Float16* __restrict__ fdh, int N)
{
    __shared__ _Float16 As[64 * 72];
    int t = threadIdx.x;
    int row0 = blockIdx.x * 64;

    // stage A once: thread handles (row r, k-group kg of 4)
#pragma unroll
    for (int i = 0; i < 2; i++) {
        int flat = i * 512 + t;
        int r = flat >> 4, kg = flat & 15;
        int gr = row0 + r;
        float4 hv = make_float4(0.f, 0.f, 0.f, 0.f);
        if (gr < N) hv = *(const float4*)(h + (size_t)gr * 64 + kg * 4);
        float4 a4 = *(const float4*)(bnA + kg * 4);
        float4 b4 = *(const float4*)(bnB + kg * 4);
        half4v o4;
        o4[0] = (_Float16)(hv.x * a4.x + b4.x);
        o4[1] = (_Float16)(hv.y * a4.y + b4.y);
        o4[2] = (_Float16)(hv.z * a4.z + b4.z);
        o4[3] = (_Float16)(hv.w * a4.w + b4.w);
        *(half4v*)(&As[r * 72 + kg * 4]) = o4;
    }
    __syncthreads();

    int w = t >> 6, lane = t & 63;
    int y = w >> 2;
    const _Float16* Wm = Wt + (size_t)y * 16384;
    const float* bias  = y ? bdst : bsrc;
    _Float16* out      = y ? fdh : fsh;
    int n16 = lane & 15, q = lane >> 4;
    int cw = (w & 3) * 64;
    f32x4 acc[4][4];
#pragma unroll
    for (int mt = 0; mt < 4; mt++)
#pragma unroll
        for (int nt = 0; nt < 4; nt++) acc[mt][nt] = (f32x4)(0.f);
    float bv[4];
#pragma unroll
    for (int nt = 0; nt < 4; nt++) bv[nt] = bias[cw + nt * 16 + n16];

#pragma unroll
    for (int kk = 0; kk < 2; kk++) {
        half8 af[4], bf[4];
#pragma unroll
        for (int mt = 0; mt < 4; mt++)
            af[mt] = *(const half8*)(&As[(mt * 16 + n16) * 72 + kk * 32 + q * 8]);
#pragma unroll
        for (int nt = 0; nt < 4; nt++)
            bf[nt] = *(const half8*)(Wm + (size_t)(cw + nt * 16 + n16) * 64 + kk * 32 + q * 8);
#pragma unroll
        for (int mt = 0; mt < 4; mt++)
#pragma unroll
            for (int nt = 0; nt < 4; nt++)
                acc[mt][nt] = __builtin_amdgcn_mfma_f32_16x16x32_f16(af[mt], bf[nt], acc[mt][nt], 0, 0, 0);
    }
#pragma unroll
    for (int mt = 0; mt < 4; mt++) {
#pragma unroll
        for (int i = 0; i < 4; i++) {
            int gr = row0 + mt * 16 + q * 4 + i;
            if (gr < N) {
#pragma unroll
                for (int nt = 0; nt < 4; nt++)
                    out[(size_t)gr * 256 + cw + nt * 16 + n16] = (_Float16)(acc[mt][nt][i] + bv[nt]);
            }
        }
    }
}

// ---------------- fused GATv2 edge phase: wave per dst node ----------------
// lane = e2*32 + d8; direct same-address col_src loads (32-lane broadcast), 1-ahead prefetch.

__global__ void __launch_bounds__(256) gat_kernel(
    const _Float16* __restrict__ fsh, const _Float16* __restrict__ fdh,
    const _Float16* __restrict__ att16,
    const int* __restrict__ row_ptr, const int* __restrict__ degv,
    const int* __restrict__ col_src,
    float* __restrict__ hmean, int N)
{
    int wid = (blockIdx.x << 2) + (threadIdx.x >> 6);
    if (wid >= N) return;
    int lane = threadIdx.x & 63;
    int e2 = lane >> 5;
    int d8 = lane & 31;
    int rs = row_ptr[wid];
    int deg = degv[wid];
    const int* cs = col_src + rs;

    half8 fdv = *(const half8*)(fdh + (size_t)wid * 256 + d8 * 8);
    half8 att = *(const half8*)(att16 + (d8 >> 3) * 64 + (d8 & 7) * 8);
    half8 k02;
#pragma unroll
    for (int j = 0; j < 8; j++) k02[j] = (_Float16)0.2f;

    float acc[8];
#pragma unroll
    for (int j = 0; j < 8; j++) acc[j] = 0.f;
    float l = 0.f;

    auto fetch = [&](int i, half8& a, half8& b, bool& va, bool& vb) {
        int idx0 = i + e2, idx1 = i + 2 + e2;
        va = idx0 < deg;
        vb = idx1 < deg;
        int c0 = va ? idx0 : 0;
        int c1 = vb ? idx1 : 0;
        int s0 = cs[c0];
        int s1 = cs[c1];
        a = *(const half8*)(fsh + (size_t)s0 * 256 + d8 * 8);
        b = *(const half8*)(fsh + (size_t)s1 * 256 + d8 * 8);
    };

    half8 ca, cb;
    bool va = false, vb = false;
    if (deg > 0) fetch(0, ca, cb, va, vb);

    for (int i = 0; i < deg; i += 4) {
        half8 na, nb;
        bool nva = false, nvb = false;
        if (i + 4 < deg) fetch(i + 4, na, nb, nva, nvb);
#pragma unroll
        for (int u = 0; u < 2; u++) {
            half8 fv = u ? cb : ca;
            bool valid = u ? vb : va;
            half8 x = fv + fdv;
            half8 lx = __builtin_elementwise_max(x, x * k02);
            float p = 0.f;
#ifdef USE_FDOT2
#pragma unroll
            for (int j = 0; j < 4; j++) {
                half2v a2 = { lx[2 * j], lx[2 * j + 1] };
                half2v b2 = { att[2 * j], att[2 * j + 1] };
                p = __builtin_amdgcn_fdot2(a2, b2, p, false);
            }
#else
#pragma unroll
            for (int j = 0; j < 8; j++) p = fmaf((float)lx[j], (float)att[j], p);
#endif
            p = dpp_sum8(p);
            float e = valid ? __expf(p) : 0.f;
            l += e;
#pragma unroll
            for (int j = 0; j < 8; j++) acc[j] = fmaf(e, (float)fv[j], acc[j]);
        }
        ca = na; cb = nb; va = nva; vb = nvb;
    }
    l += __shfl_xor(l, 32);
#pragma unroll
    for (int j = 0; j < 8; j++) acc[j] += __shfl_xor(acc[j], 32);

    float inv = (l > 0.f) ? 0.25f / l : 0.f;   // head-mean folded
    float m[8];
#pragma unroll
    for (int j = 0; j < 8; j++) m[j] = fmaxf(acc[j] * inv, 0.f);
#pragma unroll
    for (int j = 0; j < 8; j++) {
        m[j] += __shfl_xor(m[j], 8);
        m[j] += __shfl_xor(m[j], 16);
    }
    if (lane < 8) {
        float4 o0 = make_float4(m[0], m[1], m[2], m[3]);
        float4 o1 = make_float4(m[4], m[5], m[6], m[7]);
        *(float4*)(hmean + (size_t)wid * 64 + d8 * 8) = o0;
        *(float4*)(hmean + (size_t)wid * 64 + d8 * 8 + 4) = o1;
    }
}

// ------- BN stats + graph sums; last block computes pooled MLP + both BNs -------

__global__ void __launch_bounds__(256) stats_pooled_kernel(
    const float* __restrict__ hmean, const int* __restrict__ gid,
    float* __restrict__ bnsum, float* __restrict__ bnsq,
    float* __restrict__ S, const int* __restrict__ cntg,
    const float* __restrict__ bn_g, const float* __restrict__ bn_b,
    const float* __restrict__ lpW, const float* __restrict__ lpb,
    const float* __restrict__ lpg, const float* __restrict__ lpbt,
    float* __restrict__ bnA_out, float* __restrict__ bnB_out,
    float* __restrict__ p_out, int* __restrict__ done, int N)
{
    __shared__ float bs[4][64], bq[4][64];
    int t = threadIdx.x, lane = t & 63, w = t >> 6;
    int wglobal = blockIdx.x * 4 + w;
    int chunk = (N + 511) >> 9;
    int n0 = wglobal * chunk;
    int n1 = min(n0 + chunk, N);
    float sum = 0.f, sq = 0.f, run = 0.f;
    int cur = -1;
    for (int n = n0; n < n1; n++) {
        float v = hmean[(size_t)n * 64 + lane];
        int g = gid[n];
        if (g != cur) {
            if (cur >= 0) atomicAdd(&S[cur * 64 + lane], run);
            run = 0.f;
            cur = g;
        }
        run += v;
        sum += v;
        sq = fmaf(v, v, sq);
    }
    if (cur >= 0) atomicAdd(&S[cur * 64 + lane], run);
    bs[w][lane] = sum;
    bq[w][lane] = sq;
    __syncthreads();
    if (w == 0) {
        float s2 = bs[0][lane] + bs[1][lane] + bs[2][lane] + bs[3][lane];
        float q2 = bq[0][lane] + bq[1][lane] + bq[2][lane] + bq[3][lane];
        atomicAdd(&bnsum[lane], s2);
        atomicAdd(&bnsq[lane], q2);
    }
    // ---- last-block finisher ----
    __syncthreads();
    __threadfence();
    __shared__ int amLast;
    if (t == 0) amLast = (atomicAdd(done, 1) == gridDim.x - 1);
    __syncthreads();
    if (!amLast) return;

    __shared__ float Ash[64], Bsh[64];
    __shared__ float sv4[4][64];
    __shared__ float qsh[128][64];
    __shared__ float musc[64], scsh[64];
    if (t < 64) {
        float mu = vload(&bnsum[t]) / (float)N;
        float var = vload(&bnsq[t]) / (float)N - mu * mu;
        float a = bn_g[t] / sqrtf(var + 1e-5f);
        float b = bn_b[t] - mu * a;
        Ash[t] = a; Bsh[t] = b;
        bnA_out[t] = a; bnB_out[t] = b;
    }
    __syncthreads();
    int f = t & 63, gc = t >> 6;
    float qs = 0.f, qq = 0.f;
    for (int g0 = 0; g0 < 128; g0 += 4) {
        int g = g0 + gc;
        sv4[gc][f] = Ash[f] * vload(&S[g * 64 + f]) + Bsh[f] * (float)cntg[g];
        __syncthreads();
        float a = lpb[f];
#pragma unroll 16
        for (int k = 0; k < 64; k++) a = fmaf(sv4[gc][k], lpW[k * 64 + f], a);
        a = fmaxf(a, 0.f);
        qsh[g][f] = a;
        qs += a;
        qq = fmaf(a, a, qq);
        __syncthreads();
    }
    bs[gc][f] = qs;
    bq[gc][f] = qq;
    __syncthreads();
    if (t < 64) {
        float m = (bs[0][t] + bs[1][t] + bs[2][t] + bs[3][t]) * (1.f / 128.f);
        float v = (bq[0][t] + bq[1][t] + bq[2][t] + bq[3][t]) * (1.f / 128.f) - m * m;
        musc[t] = m;
        scsh[t] = lpg[t] / sqrtf(v + 1e-5f);
    }
    __syncthreads();
    for (int i = t; i < 8192; i += 256) {
        int ff = i & 63;
        p_out[i] = (qsh[i >> 6][ff] - musc[ff]) * scsh[ff] + lpbt[ff];
    }
}

// ------- head: per-graph cat GEMM; last block does BN + linear + BN + log_softmax -------

__global__ void __launch_bounds__(256) head_kernel(
    const float* __restrict__ p, const float* __restrict__ blW, const float* __restrict__ blb,
    const float* __restrict__ blg, const float* __restrict__ blbt,
    const float* __restrict__ llW, const float* __restrict__ llb,
    const float* __restrict__ llg, const float* __restrict__ llbt,
    float* __restrict__ hh, float* __restrict__ hsum, float* __restrict__ hsq,
    int* __restrict__ done, float* __restrict__ out)
{
    __shared__ float cat[192];
    __shared__ float partial[4][64];
    int g = blockIdx.x;
    int t = threadIdx.x;
    if (t < 192) cat[t] = p[(t >> 6) * 8192 + g * 64 + (t & 63)];
    __syncthreads();
    int f = t & 63, kc = t >> 6;
    float acc = 0.f;
#pragma unroll
    for (int k = kc * 48; k < kc * 48 + 48; k++)
        acc = fmaf(cat[k], blW[k * 64 + f], acc);
    partial[kc][f] = acc;
    __syncthreads();
    if (t < 64) {
        float v = partial[0][t] + partial[1][t] + partial[2][t] + partial[3][t] + blb[t];
        v = fmaxf(v, 0.f);
        hh[g * 64 + t] = v;
        atomicAdd(&hsum[t], v);
        atomicAdd(&hsq[t], v * v);
    }
    __syncthreads();
    __threadfence();
    __shared__ int amLast;
    if (t == 0) amLast = (atomicAdd(done, 1) == gridDim.x - 1);
    __syncthreads();
    if (!amLast) return;

    __shared__ float hn[128][65];
    __shared__ float ph[128][12];
    __shared__ float mu[64], sc[64];
    __shared__ float mj[12], scj[12];
    __shared__ float sW[640];
    if (t < 64) {
        float m = vload(&hsum[t]) * (1.f / 128.f);
        float v = vload(&hsq[t]) * (1.f / 128.f) - m * m;
        mu[t] = m;
        sc[t] = blg[t] / sqrtf(v + 1e-5f);
    }
    for (int i = t; i < 640; i += 256) sW[i] = llW[i];
    __syncthreads();
    for (int i = t; i < 8192; i += 256) {
        int gg = i >> 6, ff = i & 63;
        float v = (vload(&hh[i]) - mu[ff]) * sc[ff] + blbt[ff];
        out[1280 + i] = v;          // output 1: pooled_hh
        hn[gg][ff] = v;
    }
    __syncthreads();
    for (int i = t; i < 1280; i += 256) {
        int gg = i / 10, j = i - gg * 10;
        float s = llb[j];
#pragma unroll 8
        for (int k = 0; k < 64; k++) s = fmaf(hn[gg][k], sW[k * 10 + j], s);
        ph[gg][j] = fmaxf(s, 0.f);
    }
    __syncthreads();
    if (t < 10) {
        float m = 0.f;
        for (int gg = 0; gg < 128; gg++) m += ph[gg][t];
        m *= (1.f / 128.f);
        float v = 0.f;
        for (int gg = 0; gg < 128; gg++) { float d = ph[gg][t] - m; v = fmaf(d, d, v); }
        v *= (1.f / 128.f);
        mj[t] = m;
        scj[t] = llg[t] / sqrtf(v + 1e-5f);
    }
    __syncthreads();
    if (t < 128) {
        float vals[10];
        float mx = -1e30f;
        for (int j = 0; j < 10; j++) {
            vals[j] = (ph[t][j] - mj[j]) * scj[j] + llbt[j];
            mx = fmaxf(mx, vals[j]);
        }
        float se = 0.f;
        for (int j = 0; j < 10; j++) se += __expf(vals[j] - mx);
        float lse = logf(se) + mx;
        for (int j = 0; j < 10; j++) out[t * 10 + j] = vals[j] - lse;   // output 0
    }
}

// ---------------- launcher ----------------

extern "C" void kernel_launch(void* const* d_in, const int* in_sizes, int n_in,
                              void* d_out, int out_size, void* d_ws, size_t ws_size,
                              hipStream_t stream)
{
    const float* feat = (const float*)d_in[0];
    const float* Wsrc = (const float*)d_in[1];
    const float* bsrc = (const float*)d_in[2];
    const float* Wdst = (const float*)d_in[3];
    const float* bdst = (const float*)d_in[4];
    const float* attn = (const float*)d_in[5];
    const float* bn_g = (const float*)d_in[6];
    const float* bn_b = (const float*)d_in[7];
    const float* lpW  = (const float*)d_in[8];
    const float* lpb  = (const float*)d_in[9];
    const float* lpg  = (const float*)d_in[10];
    const float* lpbt = (const float*)d_in[11];
    const float* blW  = (const float*)d_in[12];
    const float* blb  = (const float*)d_in[13];
    const float* blg  = (const float*)d_in[14];
    const float* blbt = (const float*)d_in[15];
    const float* llW  = (const float*)d_in[16];
    const float* llb  = (const float*)d_in[17];
    const float* llg  = (const float*)d_in[18];
    const float* llbt = (const float*)d_in[19];
    const int* srcp = (const int*)d_in[20];
    const int* dstp = (const int*)d_in[21];
    const int* gidp = (const int*)d_in[22];
    float* out = (float*)d_out;

    int N = in_sizes[0] / 64;
    int E = in_sizes[20];
    int nb = (N + 1023) / 1024;

    // workspace layout
    float* wsf = (float*)d_ws;
    _Float16* fsh = (_Float16*)wsf;                       // N*256 f16
    _Float16* fdh = (_Float16*)(wsf + (size_t)N * 128);   // N*256 f16
    float* hmean = wsf + (size_t)N * 256;            // N*64
    float* pbuf  = hmean + (size_t)N * 64;           // 3*8192
    float* bnA   = pbuf + 24576;                     // 4*64
    float* bnB   = bnA + 256;                        // 4*64
    float* hh    = bnB + 256;                        // 8192
    _Float16* Wt16  = (_Float16*)(hh + 8192);        // 6*16384 f16 = 49152 fl
    _Float16* att16 = (_Float16*)(hh + 8192 + 49152);// 3*256 f16 = 384 fl
    float* zstart = hh + 8192 + 49152 + 384;
    float* bnsum = zstart;                           // 3*64
    float* bnsq  = bnsum + 192;                      // 3*64
    float* hsum  = bnsq + 192;                       // 64
    float* hsq   = hsum + 64;                        // 64
    float* S     = hsq + 64;                         // 3*8192
    int* deg     = (int*)(S + 24576);                // N
    int* cursor  = deg + N;                          // N
    int* gbase   = cursor + N;                       // 1
    int* done    = gbase + 1;                        // 4
    int* zend    = done + 4;
    int* cntg    = zend;                             // 128
    int* gstart  = cntg + 128;                       // 128
    int* row_ptr = gstart + 128;                     // N
    int* col_src = row_ptr + N;                      // E

    size_t zbytes = (size_t)((char*)zend - (char*)zstart);
    hipMemsetAsync(zstart, 0, zbytes, stream);
    hipLaunchKernelGGL(wcvt_kernel, dim3(6), dim3(256), 0, stream,
                       Wsrc, Wdst, attn, Wt16, att16, bnA, bnB);
    int mEN = (E > N) ? E : N;
    hipLaunchKernelGGL(hb_kernel, dim3((mEN + 255) / 256), dim3(256), 0, stream,
                       dstp, deg, gidp, gstart, N, E);
    hipLaunchKernelGGL(rowptr_kernel, dim3(nb), dim3(256), 0, stream,
                       deg, row_ptr, gbase, gstart, cntg, N);
    hipLaunchKernelGGL(scatter_kernel, dim3((E + 255) / 256), dim3(256), 0, stream,
                       srcp, dstp, row_ptr, cursor, col_src, E);

    for (int l = 0; l < 3; l++) {
        const float* hsrcp = (l == 0) ? feat : hmean;
        hipLaunchKernelGGL(gemm_kernel, dim3((N + 63) / 64), dim3(512), 0, stream,
                           hsrcp, bnA + l * 64, bnB + l * 64,
                           Wt16 + (size_t)l * 32768, bsrc + l * 256, bdst + l * 256,
                           fsh, fdh, N);
        hipLaunchKernelGGL(gat_kernel, dim3((N + 3) / 4), dim3(256), 0, stream,
                           fsh, fdh, att16 + l * 256, row_ptr, deg, col_src, hmean, N);
        hipLaunchKernelGGL(stats_pooled_kernel, dim3(128), dim3(256), 0, stream,
                           hmean, gidp, bnsum + l * 64, bnsq + l * 64, S + l * 8192, cntg,
                           bn_g + l * 64, bn_b + l * 64,
                           lpW + (size_t)l * 4096, lpb + l * 64, lpg + l * 64, lpbt + l * 64,
                           bnA + (l + 1) * 64, bnB + (l + 1) * 64,
                           pbuf + l * 8192, done + l, N);
    }
    hipLaunchKernelGGL(head_kernel, dim3(128), dim3(256), 0, stream,
                       pbuf, blW, blb, blg, blbt, llW, llb, llg, llbt,
                       hh, hsum, hsq, done + 3, out);
}

// Round 7
// 578.608 us; speedup vs baseline: 1.2341x; 1.2341x over previous
//
#include <hip/hip_runtime.h>
#include <cmath>

#define NH 4
#define NG 128

typedef _Float16 half8 __attribute__((ext_vector_type(8)));
typedef _Float16 half4v __attribute__((ext_vector_type(4)));
typedef _Float16 half2v __attribute__((ext_vector_type(2)));
typedef float f32x4 __attribute__((ext_vector_type(4)));

#if defined(__has_builtin)
# if __has_builtin(__builtin_amdgcn_fdot2)
#  define USE_FDOT2 1
# endif
# if __has_builtin(__builtin_amdgcn_update_dpp)
#  define USE_DPP 1
# endif
#endif

// sum over each aligned 8-lane group, all lanes get result
__device__ inline float dpp_sum8(float p) {
#ifdef USE_DPP
    int pi = __builtin_bit_cast(int, p);
    int a = __builtin_amdgcn_update_dpp(0, pi, 0xB1, 0xF, 0xF, true);   // quad_perm [1,0,3,2]
    p += __builtin_bit_cast(float, a);
    pi = __builtin_bit_cast(int, p);
    a = __builtin_amdgcn_update_dpp(0, pi, 0x4E, 0xF, 0xF, true);       // quad_perm [2,3,0,1]
    p += __builtin_bit_cast(float, a);
    pi = __builtin_bit_cast(int, p);
    a = __builtin_amdgcn_update_dpp(0, pi, 0x141, 0xF, 0xF, true);      // row_half_mirror
    p += __builtin_bit_cast(float, a);
    return p;
#else
    p += __shfl_xor(p, 1); p += __shfl_xor(p, 2); p += __shfl_xor(p, 4);
    return p;
#endif
}

// ---------------- CSR build: hist + graph bounds in one dispatch ----------------

__global__ void __launch_bounds__(256) hb_kernel(const int* __restrict__ dst,
                                                 int* __restrict__ deg,
                                                 const int* __restrict__ gid,
                                                 int* __restrict__ gstart, int N, int E) {
    int i = blockIdx.x * 256 + threadIdx.x;
    if (i < E) atomicAdd(&deg[dst[i]], 1);
    if (i < N) {
        int a = gid[i];
        if (i == 0)
            for (int g = 0; g <= a; g++) gstart[g] = 0;
        int b = (i + 1 < N) ? gid[i + 1] : NG;
        for (int g = a + 1; g <= b && g < NG; g++) gstart[g] = i + 1;
    }
}

// single-dispatch row offsets: per-block scan + atomic base (regions unordered; deg[] kept)
__global__ void __launch_bounds__(256) rowptr_kernel(const int* __restrict__ deg,
                                                     int* __restrict__ row_ptr,
                                                     int* __restrict__ gbase,
                                                     const int* __restrict__ gstart,
                                                     int* __restrict__ cntg, int N) {
    __shared__ int red[256];
    __shared__ int base_s;
    int t = threadIdx.x;
    int base = blockIdx.x * 1024 + t * 4;
    int d[4];
    int s = 0;
#pragma unroll
    for (int j = 0; j < 4; j++) {
        int i = base + j;
        d[j] = (i < N) ? deg[i] : 0;
        s += d[j];
    }
    red[t] = s;
    __syncthreads();
    for (int off = 1; off < 256; off <<= 1) {
        int v = (t >= off) ? red[t - off] : 0;
        __syncthreads();
        red[t] += v;
        __syncthreads();
    }
    if (t == 255) base_s = atomicAdd(gbase, red[255]);
    __syncthreads();
    int excl = red[t] - s + base_s;
#pragma unroll
    for (int j = 0; j < 4; j++) {
        int i = base + j;
        if (i < N) row_ptr[i] = excl;
        excl += d[j];
    }
    if (blockIdx.x == 0 && t < NG) {
        int s1 = (t == NG - 1) ? N : gstart[t + 1];
        cntg[t] = s1 - gstart[t];
    }
}

__global__ void __launch_bounds__(256) scatter_kernel(const int* __restrict__ src,
                                                      const int* __restrict__ dst,
                                                      const int* __restrict__ row_ptr,
                                                      int* __restrict__ cursor,
                                                      int* __restrict__ col_src, int E) {
    int e = blockIdx.x * 256 + threadIdx.x;
    if (e < E) {
        int d = dst[e];
        int pos = row_ptr[d] + atomicAdd(&cursor[d], 1);
        col_src[pos] = src[e];
    }
}

// ------- one-time: W -> Wt[c][k] f16 (24 parallel 64x64 tiles); attn f16; bnA/bnB -------

__global__ void __launch_bounds__(256) wcvt_kernel(
    const float* __restrict__ Wsrc, const float* __restrict__ Wdst,
    const float* __restrict__ attn,
    _Float16* __restrict__ Wt, _Float16* __restrict__ att16,
    float* bnA, float* bnB)
{
    __shared__ _Float16 lt[64 * 68];
    int b = blockIdx.x;
    int mat = b >> 2, ct = b & 3;
    int c0 = ct * 64;
    const float* W = ((mat & 1) ? Wdst : Wsrc) + (size_t)(mat >> 1) * 16384;
    _Float16* o = Wt + (size_t)mat * 16384;
    int t = threadIdx.x;
#pragma unroll
    for (int i = 0; i < 16; i++) {
        int flat = i * 256 + t;
        int k = flat >> 6, c = flat & 63;
        lt[c * 68 + k] = (_Float16)W[k * 256 + c0 + c];
    }
    __syncthreads();
#pragma unroll
    for (int i = 0; i < 16; i++) {
        int flat = i * 256 + t;
        int c = flat >> 6, k = flat & 63;
        o[(size_t)(c0 + c) * 64 + k] = lt[c * 68 + k];
    }
    if (b == 0) {
        if (t < 64) { bnA[t] = 1.f; bnB[t] = 0.f; }
        for (int i = t; i < 3 * 256; i += 256) att16[i] = (_Float16)attn[i];
    }
}

// ---------------- fused BN-affine + dual GEMM (f16 MFMA), fs+fd in one block ----------

__global__ void __launch_bounds__(512) gemm_kernel(
    const float* __restrict__ h, const float* __restrict__ bnA, const float* __restrict__ bnB,
    const _Float16* __restrict__ Wt,            // [2][256][64] f16 for this layer
    const float* __restrict__ bsrc, const float* __restrict__ bdst,
    _Float16* __restrict__ fsh, _Float16* __restrict__ fdh, int N)
{
    __shared__ _Float16 As[64 * 72];
    int t = threadIdx.x;
    int row0 = blockIdx.x * 64;

#pragma unroll
    for (int i = 0; i < 2; i++) {
        int flat = i * 512 + t;
        int r = flat >> 4, kg = flat & 15;
        int gr = row0 + r;
        float4 hv = make_float4(0.f, 0.f, 0.f, 0.f);
        if (gr < N) hv = *(const float4*)(h + (size_t)gr * 64 + kg * 4);
        float4 a4 = *(const float4*)(bnA + kg * 4);
        float4 b4 = *(const float4*)(bnB + kg * 4);
        half4v o4;
        o4[0] = (_Float16)(hv.x * a4.x + b4.x);
        o4[1] = (_Float16)(hv.y * a4.y + b4.y);
        o4[2] = (_Float16)(hv.z * a4.z + b4.z);
        o4[3] = (_Float16)(hv.w * a4.w + b4.w);
        *(half4v*)(&As[r * 72 + kg * 4]) = o4;
    }
    __syncthreads();

    int w = t >> 6, lane = t & 63;
    int y = w >> 2;
    const _Float16* Wm = Wt + (size_t)y * 16384;
    const float* bias  = y ? bdst : bsrc;
    _Float16* out      = y ? fdh : fsh;
    int n16 = lane & 15, q = lane >> 4;
    int cw = (w & 3) * 64;
    f32x4 acc[4][4];
#pragma unroll
    for (int mt = 0; mt < 4; mt++)
#pragma unroll
        for (int nt = 0; nt < 4; nt++) acc[mt][nt] = (f32x4)(0.f);
    float bv[4];
#pragma unroll
    for (int nt = 0; nt < 4; nt++) bv[nt] = bias[cw + nt * 16 + n16];

#pragma unroll
    for (int kk = 0; kk < 2; kk++) {
        half8 af[4], bf[4];
#pragma unroll
        for (int mt = 0; mt < 4; mt++)
            af[mt] = *(const half8*)(&As[(mt * 16 + n16) * 72 + kk * 32 + q * 8]);
#pragma unroll
        for (int nt = 0; nt < 4; nt++)
            bf[nt] = *(const half8*)(Wm + (size_t)(cw + nt * 16 + n16) * 64 + kk * 32 + q * 8);
#pragma unroll
        for (int mt = 0; mt < 4; mt++)
#pragma unroll
            for (int nt = 0; nt < 4; nt++)
                acc[mt][nt] = __builtin_amdgcn_mfma_f32_16x16x32_f16(af[mt], bf[nt], acc[mt][nt], 0, 0, 0);
    }
#pragma unroll
    for (int mt = 0; mt < 4; mt++) {
#pragma unroll
        for (int i = 0; i < 4; i++) {
            int gr = row0 + mt * 16 + q * 4 + i;
            if (gr < N) {
#pragma unroll
                for (int nt = 0; nt < 4; nt++)
                    out[(size_t)gr * 256 + cw + nt * 16 + n16] = (_Float16)(acc[mt][nt][i] + bv[nt]);
            }
        }
    }
}

// ---------------- fused GATv2 edge phase: wave per dst node ----------------
// lane = e2*32 + d8. Unconditional main loop over deg&~3 edges (no masks), masked tail <=3.

__global__ void __launch_bounds__(256) gat_kernel(
    const _Float16* __restrict__ fsh, const _Float16* __restrict__ fdh,
    const _Float16* __restrict__ att16,
    const int* __restrict__ row_ptr, const int* __restrict__ degv,
    const int* __restrict__ col_src,
    float* __restrict__ hmean, int N)
{
    int wid = (blockIdx.x << 2) + (threadIdx.x >> 6);
    if (wid >= N) return;
    int lane = threadIdx.x & 63;
    int e2 = lane >> 5;
    int d8 = lane & 31;
    int rs = row_ptr[wid];
    int deg = degv[wid];
    const int* cs = col_src + rs;

    half8 fdv = *(const half8*)(fdh + (size_t)wid * 256 + d8 * 8);
    half8 att = *(const half8*)(att16 + (d8 >> 3) * 64 + (d8 & 7) * 8);
    half8 k02;
#pragma unroll
    for (int j = 0; j < 8; j++) k02[j] = (_Float16)0.2f;

    float acc[8];
#pragma unroll
    for (int j = 0; j < 8; j++) acc[j] = 0.f;
    float l = 0.f;

    auto body = [&](half8 fv) {
        half8 x = fv + fdv;
        half8 lx = __builtin_elementwise_max(x, x * k02);
        float p = 0.f;
#ifdef USE_FDOT2
#pragma unroll
        for (int j = 0; j < 4; j++) {
            half2v a2 = { lx[2 * j], lx[2 * j + 1] };
            half2v b2 = { att[2 * j], att[2 * j + 1] };
            p = __builtin_amdgcn_fdot2(a2, b2, p, false);
        }
#else
#pragma unroll
        for (int j = 0; j < 8; j++) p = fmaf((float)lx[j], (float)att[j], p);
#endif
        p = dpp_sum8(p);
        float e = __expf(p);
        l += e;
#pragma unroll
        for (int j = 0; j < 8; j++) acc[j] = fmaf(e, (float)fv[j], acc[j]);
    };

    int deg4 = deg & ~3;
    half8 ca, cb;
    if (deg4 > 0) {
        int s0 = cs[e2];
        int s1 = cs[2 + e2];
        ca = *(const half8*)(fsh + (size_t)s0 * 256 + d8 * 8);
        cb = *(const half8*)(fsh + (size_t)s1 * 256 + d8 * 8);
    }
    for (int i = 0; i < deg4; i += 4) {
        half8 na = ca, nb = cb;
        if (i + 4 < deg4) {
            int s0 = cs[i + 4 + e2];
            int s1 = cs[i + 6 + e2];
            na = *(const half8*)(fsh + (size_t)s0 * 256 + d8 * 8);
            nb = *(const half8*)(fsh + (size_t)s1 * 256 + d8 * 8);
        }
        body(ca);
        body(cb);
        ca = na; cb = nb;
    }
    // tail: up to 3 edges; e2 halves diverge but 8-lane groups stay uniform
    for (int idx = deg4 + e2; idx < deg; idx += 2) {
        int s = cs[idx];
        half8 fv = *(const half8*)(fsh + (size_t)s * 256 + d8 * 8);
        body(fv);
    }

    l += __shfl_xor(l, 32);
#pragma unroll
    for (int j = 0; j < 8; j++) acc[j] += __shfl_xor(acc[j], 32);

    float inv = (l > 0.f) ? 0.25f / l : 0.f;   // head-mean folded
    float m[8];
#pragma unroll
    for (int j = 0; j < 8; j++) m[j] = fmaxf(acc[j] * inv, 0.f);
#pragma unroll
    for (int j = 0; j < 8; j++) {
        m[j] += __shfl_xor(m[j], 8);
        m[j] += __shfl_xor(m[j], 16);
    }
    if (lane < 8) {
        float4 o0 = make_float4(m[0], m[1], m[2], m[3]);
        float4 o1 = make_float4(m[4], m[5], m[6], m[7]);
        *(float4*)(hmean + (size_t)wid * 64 + d8 * 8) = o0;
        *(float4*)(hmean + (size_t)wid * 64 + d8 * 8 + 4) = o1;
    }
}

// ---------------- BN stats + graph segment sums (raw hmean) ----------------

__global__ void __launch_bounds__(256) stats_kernel(
    const float* __restrict__ hmean, const int* __restrict__ gid,
    float* __restrict__ bnsum, float* __restrict__ bnsumsq,
    float* __restrict__ S, int N)
{
    __shared__ float bs[4][64], bq[4][64];
    int t = threadIdx.x, lane = t & 63, w = t >> 6;
    int wglobal = blockIdx.x * 4 + w;
    int chunk = (N + 511) >> 9;
    int n0 = wglobal * chunk;
    int n1 = min(n0 + chunk, N);
    float sum = 0.f, sq = 0.f, run = 0.f;
    int cur = -1;
    for (int n = n0; n < n1; n++) {
        float v = hmean[(size_t)n * 64 + lane];
        int g = gid[n];
        if (g != cur) {
            if (cur >= 0) atomicAdd(&S[cur * 64 + lane], run);
            run = 0.f;
            cur = g;
        }
        run += v;
        sum += v;
        sq = fmaf(v, v, sq);
    }
    if (cur >= 0) atomicAdd(&S[cur * 64 + lane], run);
    bs[w][lane] = sum;
    bq[w][lane] = sq;
    __syncthreads();
    if (w == 0) {
        float s2 = bs[0][lane] + bs[1][lane] + bs[2][lane] + bs[3][lane];
        float q2 = bq[0][lane] + bq[1][lane] + bq[2][lane] + bq[3][lane];
        atomicAdd(&bnsum[lane], s2);
        atomicAdd(&bnsumsq[lane], q2);
    }
}

// ---------------- pooled path A: per-graph MLP row (128 blocks) ----------------

__global__ void __launch_bounds__(256) pooled_a_kernel(
    const float* __restrict__ bnsum, const float* __restrict__ bnsumsq,
    const float* __restrict__ S, const int* __restrict__ cntg,
    const float* __restrict__ bn_g, const float* __restrict__ bn_b,
    const float* __restrict__ lpW, const float* __restrict__ lpb,
    float* __restrict__ q, float* __restrict__ qsum, float* __restrict__ qsq, int N)
{
    __shared__ float sv[64];
    __shared__ float partial[4][64];
    int g = blockIdx.x;
    int t = threadIdx.x;
    if (t < 64) {
        float mu = bnsum[t] / (float)N;
        float var = bnsumsq[t] / (float)N - mu * mu;
        float a = bn_g[t] / sqrtf(var + 1e-5f);
        float b = bn_b[t] - mu * a;
        sv[t] = a * S[g * 64 + t] + b * (float)cntg[g];
    }
    __syncthreads();
    int f = t & 63, kc = t >> 6;
    float acc = 0.f;
#pragma unroll
    for (int k = kc * 16; k < kc * 16 + 16; k++)
        acc = fmaf(sv[k], lpW[k * 64 + f], acc);
    partial[kc][f] = acc;
    __syncthreads();
    if (t < 64) {
        float v = partial[0][t] + partial[1][t] + partial[2][t] + partial[3][t] + lpb[t];
        v = fmaxf(v, 0.f);
        q[g * 64 + t] = v;
        atomicAdd(&qsum[t], v);
        atomicAdd(&qsq[t], v * v);
    }
}

// ---------------- pooled path B: BN over graphs + next-layer node-BN affine ----------------

__global__ void __launch_bounds__(256) pooled_b_kernel(
    const float* __restrict__ bnsum, const float* __restrict__ bnsumsq,
    const float* __restrict__ q, const float* __restrict__ qsum, const float* __restrict__ qsq,
    const float* __restrict__ bn_g, const float* __restrict__ bn_b,
    const float* __restrict__ lpg, const float* __restrict__ lpbt,
    float* __restrict__ bnA_out, float* __restrict__ bnB_out,
    float* __restrict__ p_out, int N)
{
    __shared__ float mu2[64], sc2[64];
    int t = threadIdx.x;
    if (t < 64) {
        float mu = bnsum[t] / (float)N;
        float var = bnsumsq[t] / (float)N - mu * mu;
        float a = bn_g[t] / sqrtf(var + 1e-5f);
        bnA_out[t] = a;
        bnB_out[t] = bn_b[t] - mu * a;
        float m = qsum[t] * (1.f / 128.f);
        float v = qsq[t] * (1.f / 128.f) - m * m;
        mu2[t] = m;
        sc2[t] = lpg[t] / sqrtf(v + 1e-5f);
    }
    __syncthreads();
    for (int i = t; i < 128 * 64; i += 256) {
        int ff = i & 63;
        p_out[i] = (q[i] - mu2[ff]) * sc2[ff] + lpbt[ff];
    }
}

// ---------------- head A: hh = relu(cat @ blW + blb), 128 blocks, stats atomics ----------------

__global__ void __launch_bounds__(256) head_gemm_kernel(
    const float* __restrict__ p, const float* __restrict__ blW, const float* __restrict__ blb,
    float* __restrict__ hh, float* __restrict__ hsum, float* __restrict__ hsq)
{
    __shared__ float cat[192];
    __shared__ float partial[4][64];
    int g = blockIdx.x;
    int t = threadIdx.x;
    if (t < 192) cat[t] = p[(t >> 6) * 8192 + g * 64 + (t & 63)];
    __syncthreads();
    int f = t & 63, kc = t >> 6;
    float acc = 0.f;
#pragma unroll
    for (int k = kc * 48; k < kc * 48 + 48; k++)
        acc = fmaf(cat[k], blW[k * 64 + f], acc);
    partial[kc][f] = acc;
    __syncthreads();
    if (t < 64) {
        float v = partial[0][t] + partial[1][t] + partial[2][t] + partial[3][t] + blb[t];
        v = fmaxf(v, 0.f);
        hh[g * 64 + t] = v;
        atomicAdd(&hsum[t], v);
        atomicAdd(&hsq[t], v * v);
    }
}

// ---------------- head B: BN, second linear, BN, log_softmax ----------------

__global__ void __launch_bounds__(256) head_finish_kernel(
    const float* __restrict__ hh, const float* __restrict__ hsum, const float* __restrict__ hsq,
    const float* __restrict__ blg, const float* __restrict__ blbt,
    const float* __restrict__ llW, const float* __restrict__ llb,
    const float* __restrict__ llg, const float* __restrict__ llbt,
    float* __restrict__ out)
{
    __shared__ float hn[128][65];
    __shared__ float ph[128][12];
    __shared__ float mu[64], sc[64];
    __shared__ float mj[12], scj[12];
    __shared__ float sW[640];
    int t = threadIdx.x;
    if (t < 64) {
        float m = hsum[t] * (1.f / 128.f);
        float v = hsq[t] * (1.f / 128.f) - m * m;
        mu[t] = m;
        sc[t] = blg[t] / sqrtf(v + 1e-5f);
    }
    for (int i = t; i < 640; i += 256) sW[i] = llW[i];
    __syncthreads();
    for (int i = t; i < 8192; i += 256) {
        int g = i >> 6, ff = i & 63;
        float v = (hh[i] - mu[ff]) * sc[ff] + blbt[ff];
        out[1280 + i] = v;          // output 1: pooled_hh
        hn[g][ff] = v;
    }
    __syncthreads();
    for (int i = t; i < 1280; i += 256) {
        int g = i / 10, j = i - g * 10;
        float s = llb[j];
#pragma unroll 8
        for (int k = 0; k < 64; k++) s = fmaf(hn[g][k], sW[k * 10 + j], s);
        ph[g][j] = fmaxf(s, 0.f);
    }
    __syncthreads();
    if (t < 10) {
        float m = 0.f;
        for (int g = 0; g < 128; g++) m += ph[g][t];
        m *= (1.f / 128.f);
        float v = 0.f;
        for (int g = 0; g < 128; g++) { float d = ph[g][t] - m; v = fmaf(d, d, v); }
        v *= (1.f / 128.f);
        mj[t] = m;
        scj[t] = llg[t] / sqrtf(v + 1e-5f);
    }
    __syncthreads();
    if (t < 128) {
        float vals[10];
        float mx = -1e30f;
        for (int j = 0; j < 10; j++) {
            vals[j] = (ph[t][j] - mj[j]) * scj[j] + llbt[j];
            mx = fmaxf(mx, vals[j]);
        }
        float se = 0.f;
        for (int j = 0; j < 10; j++) se += __expf(vals[j] - mx);
        float lse = logf(se) + mx;
        for (int j = 0; j < 10; j++) out[t * 10 + j] = vals[j] - lse;   // output 0
    }
}

// ---------------- launcher ----------------

extern "C" void kernel_launch(void* const* d_in, const int* in_sizes, int n_in,
                              void* d_out, int out_size, void* d_ws, size_t ws_size,
                              hipStream_t stream)
{
    const float* feat = (const float*)d_in[0];
    const float* Wsrc = (const float*)d_in[1];
    const float* bsrc = (const float*)d_in[2];
    const float* Wdst = (const float*)d_in[3];
    const float* bdst = (const float*)d_in[4];
    const float* attn = (const float*)d_in[5];
    const float* bn_g = (const float*)d_in[6];
    const float* bn_b = (const float*)d_in[7];
    const float* lpW  = (const float*)d_in[8];
    const float* lpb  = (const float*)d_in[9];
    const float* lpg  = (const float*)d_in[10];
    const float* lpbt = (const float*)d_in[11];
    const float* blW  = (const float*)d_in[12];
    const float* blb  = (const float*)d_in[13];
    const float* blg  = (const float*)d_in[14];
    const float* blbt = (const float*)d_in[15];
    const float* llW  = (const float*)d_in[16];
    const float* llb  = (const float*)d_in[17];
    const float* llg  = (const float*)d_in[18];
    const float* llbt = (const float*)d_in[19];
    const int* srcp = (const int*)d_in[20];
    const int* dstp = (const int*)d_in[21];
    const int* gidp = (const int*)d_in[22];
    float* out = (float*)d_out;

    int N = in_sizes[0] / 64;
    int E = in_sizes[20];
    int nb = (N + 1023) / 1024;

    // workspace layout
    float* wsf = (float*)d_ws;
    _Float16* fsh = (_Float16*)wsf;                       // N*256 f16
    _Float16* fdh = (_Float16*)(wsf + (size_t)N * 128);   // N*256 f16
    float* hmean = wsf + (size_t)N * 256;            // N*64
    float* pbuf  = hmean + (size_t)N * 64;           // 3*8192
    float* bnA   = pbuf + 24576;                     // 4*64
    float* bnB   = bnA + 256;                        // 4*64
    float* q     = bnB + 256;                        // 8192
    float* hh    = q + 8192;                         // 8192
    _Float16* Wt16  = (_Float16*)(hh + 8192);        // 6*16384 f16 = 49152 fl
    _Float16* att16 = (_Float16*)(hh + 8192 + 49152);// 3*256 f16 = 384 fl
    float* zstart = hh + 8192 + 49152 + 384;
    float* bnsum = zstart;                           // 3*64
    float* bnsq  = bnsum + 192;                      // 3*64
    float* qsum  = bnsq + 192;                       // 3*64
    float* qsq   = qsum + 192;                       // 3*64
    float* hsum  = qsq + 192;                        // 64
    float* hsq   = hsum + 64;                        // 64
    float* S     = hsq + 64;                         // 3*8192
    int* deg     = (int*)(S + 24576);                // N
    int* cursor  = deg + N;                          // N
    int* gbase   = cursor + N;                       // 1
    int* zend    = gbase + 1;
    int* cntg    = zend;                             // 128
    int* gstart  = cntg + 128;                       // 128
    int* row_ptr = gstart + 128;                     // N
    int* col_src = row_ptr + N;                      // E

    size_t zbytes = (size_t)((char*)zend - (char*)zstart);
    hipMemsetAsync(zstart, 0, zbytes, stream);
    hipLaunchKernelGGL(wcvt_kernel, dim3(24), dim3(256), 0, stream,
                       Wsrc, Wdst, attn, Wt16, att16, bnA, bnB);
    int mEN = (E > N) ? E : N;
    hipLaunchKernelGGL(hb_kernel, dim3((mEN + 255) / 256), dim3(256), 0, stream,
                       dstp, deg, gidp, gstart, N, E);
    hipLaunchKernelGGL(rowptr_kernel, dim3(nb), dim3(256), 0, stream,
                       deg, row_ptr, gbase, gstart, cntg, N);
    hipLaunchKernelGGL(scatter_kernel, dim3((E + 255) / 256), dim3(256), 0, stream,
                       srcp, dstp, row_ptr, cursor, col_src, E);

    for (int l = 0; l < 3; l++) {
        const float* hsrcp = (l == 0) ? feat : hmean;
        hipLaunchKernelGGL(gemm_kernel, dim3((N + 63) / 64), dim3(512), 0, stream,
                           hsrcp, bnA + l * 64, bnB + l * 64,
                           Wt16 + (size_t)l * 32768, bsrc + l * 256, bdst + l * 256,
                           fsh, fdh, N);
        hipLaunchKernelGGL(gat_kernel, dim3((N + 3) / 4), dim3(256), 0, stream,
                           fsh, fdh, att16 + l * 256, row_ptr, deg, col_src, hmean, N);
        hipLaunchKernelGGL(stats_kernel, dim3(128), dim3(256), 0, stream,
                           hmean, gidp, bnsum + l * 64, bnsq + l * 64, S + l * 8192, N);
        hipLaunchKernelGGL(pooled_a_kernel, dim3(128), dim3(256), 0, stream,
                           bnsum + l * 64, bnsq + l * 64, S + l * 8192, cntg,
                           bn_g + l * 64, bn_b + l * 64,
                           lpW + (size_t)l * 4096, lpb + l * 64,
                           q, qsum + l * 64, qsq + l * 64, N);
        hipLaunchKernelGGL(pooled_b_kernel, dim3(1), dim3(256), 0, stream,
                           bnsum + l * 64, bnsq + l * 64, q, qsum + l * 64, qsq + l * 64,
                           bn_g + l * 64, bn_b + l * 64, lpg + l * 64, lpbt + l * 64,
                           bnA + (l + 1) * 64, bnB + (l + 1) * 64, pbuf + l * 8192, N);
    }
    hipLaunchKernelGGL(head_gemm_kernel, dim3(128), dim3(256), 0, stream,
                       pbuf, blW, blb, hh, hsum, hsq);
    hipLaunchKernelGGL(head_finish_kernel, dim3(1), dim3(256), 0, stream,
                       hh, hsum, hsq, blg, blbt, llW, llb, llg, llbt, out);
}

// Round 8
// 529.742 us; speedup vs baseline: 1.3480x; 1.0922x over previous
//
#include <hip/hip_runtime.h>
#include <cmath>

#define NH 4
#define NG 128

typedef _Float16 half8 __attribute__((ext_vector_type(8)));
typedef _Float16 half4v __attribute__((ext_vector_type(4)));
typedef _Float16 half2v __attribute__((ext_vector_type(2)));
typedef float f32x4 __attribute__((ext_vector_type(4)));

#if defined(__has_builtin)
# if __has_builtin(__builtin_amdgcn_fdot2)
#  define USE_FDOT2 1
# endif
# if __has_builtin(__builtin_amdgcn_update_dpp)
#  define USE_DPP 1
# endif
# if __has_builtin(__builtin_amdgcn_exp2f)
#  define EX2(x) __builtin_amdgcn_exp2f(x)
# endif
#endif
#ifndef EX2
# define EX2(x) exp2f(x)
#endif

__device__ inline float dpp_sum8(float p) {
#ifdef USE_DPP
    int pi = __builtin_bit_cast(int, p);
    int a = __builtin_amdgcn_update_dpp(0, pi, 0xB1, 0xF, 0xF, true);
    p += __builtin_bit_cast(float, a);
    pi = __builtin_bit_cast(int, p);
    a = __builtin_amdgcn_update_dpp(0, pi, 0x4E, 0xF, 0xF, true);
    p += __builtin_bit_cast(float, a);
    pi = __builtin_bit_cast(int, p);
    a = __builtin_amdgcn_update_dpp(0, pi, 0x141, 0xF, 0xF, true);
    p += __builtin_bit_cast(float, a);
    return p;
#else
    p += __shfl_xor(p, 1); p += __shfl_xor(p, 2); p += __shfl_xor(p, 4);
    return p;
#endif
}

// ------- fused: W->Wt[c][k] f16 (24 tile-blocks) + hist/pos + graph bounds -------

__global__ void __launch_bounds__(256) wcvt_hb_kernel(
    const float* __restrict__ Wsrc, const float* __restrict__ Wdst,
    const float* __restrict__ attn,
    _Float16* __restrict__ Wt, _Float16* __restrict__ att16,
    const int* __restrict__ dst, int* __restrict__ deg, int* __restrict__ pos,
    const int* __restrict__ gid, int* __restrict__ gstart, int N, int E)
{
    int t = threadIdx.x;
    if (blockIdx.x < 24) {
        __shared__ _Float16 lt[64 * 68];
        int b = blockIdx.x;
        int mat = b >> 2, ct = b & 3;
        int c0 = ct * 64;
        const float* W = ((mat & 1) ? Wdst : Wsrc) + (size_t)(mat >> 1) * 16384;
        _Float16* o = Wt + (size_t)mat * 16384;
#pragma unroll
        for (int i = 0; i < 16; i++) {
            int flat = i * 256 + t;
            int k = flat >> 6, c = flat & 63;
            lt[c * 68 + k] = (_Float16)W[k * 256 + c0 + c];
        }
        __syncthreads();
#pragma unroll
        for (int i = 0; i < 16; i++) {
            int flat = i * 256 + t;
            int c = flat >> 6, k = flat & 63;
            o[(size_t)(c0 + c) * 64 + k] = lt[c * 68 + k];
        }
        if (b == 0)
            for (int i = t; i < 3 * 256; i += 256)
                att16[i] = (_Float16)(attn[i] * 1.44269504f);   // fold log2(e) into att
        return;
    }
    int i = (blockIdx.x - 24) * 256 + t;
    if (i < E) pos[i] = atomicAdd(&deg[dst[i]], 1);
    if (i < N) {
        int a = gid[i];
        if (i == 0)
            for (int g = 0; g <= a; g++) gstart[g] = 0;
        int b2 = (i + 1 < N) ? gid[i + 1] : NG;
        for (int g = a + 1; g <= b2 && g < NG; g++) gstart[g] = i + 1;
    }
}

// single-dispatch row offsets, rows padded to multiples of 4 (for int4 col_src loads)
__global__ void __launch_bounds__(256) rowptr_kernel(const int* __restrict__ deg,
                                                     int* __restrict__ row_ptr,
                                                     int* __restrict__ gbase,
                                                     const int* __restrict__ gstart,
                                                     int* __restrict__ cntg, int N) {
    __shared__ int red[256];
    __shared__ int base_s;
    int t = threadIdx.x;
    int base = blockIdx.x * 1024 + t * 4;
    int dp[4];
    int s = 0;
#pragma unroll
    for (int j = 0; j < 4; j++) {
        int i = base + j;
        int d = (i < N) ? deg[i] : 0;
        dp[j] = (d + 3) & ~3;
        s += dp[j];
    }
    red[t] = s;
    __syncthreads();
    for (int off = 1; off < 256; off <<= 1) {
        int v = (t >= off) ? red[t - off] : 0;
        __syncthreads();
        red[t] += v;
        __syncthreads();
    }
    if (t == 255) base_s = atomicAdd(gbase, red[255]);
    __syncthreads();
    int excl = red[t] - s + base_s;
#pragma unroll
    for (int j = 0; j < 4; j++) {
        int i = base + j;
        if (i < N) row_ptr[i] = excl;
        excl += dp[j];
    }
    if (blockIdx.x == 0 && t < NG) {
        int s1 = (t == NG - 1) ? N : gstart[t + 1];
        cntg[t] = s1 - gstart[t];
    }
}

// ------- fused BN-affine + dual GEMM (f16 MFMA); extra blocks do atomic-free scatter -------

__global__ void __launch_bounds__(512) gemm_kernel(
    const float* __restrict__ h,
    const float* __restrict__ bnsum, const float* __restrict__ bnsq,
    const float* __restrict__ bn_g, const float* __restrict__ bn_b,
    int isl0, float invN,
    const _Float16* __restrict__ Wt,
    const float* __restrict__ bsrc, const float* __restrict__ bdst,
    _Float16* __restrict__ fsh, _Float16* __restrict__ fdh, int N, int gemmBlocks,
    const int* __restrict__ src, const int* __restrict__ dst,
    const int* __restrict__ row_ptr, const int* __restrict__ pos,
    int* __restrict__ col_src, int E)
{
    int t = threadIdx.x;
    if (blockIdx.x >= gemmBlocks) {          // scatter role
        int e = (blockIdx.x - gemmBlocks) * 512 + t;
        if (e < E) {
            int d = dst[e];
            col_src[row_ptr[d] + pos[e]] = src[e];
        }
        return;
    }
    __shared__ _Float16 As[64 * 72];
    int row0 = blockIdx.x * 64;

#pragma unroll
    for (int i = 0; i < 2; i++) {
        int flat = i * 512 + t;
        int r = flat >> 4, kg = flat & 15;
        int gr = row0 + r;
        float4 hv = make_float4(0.f, 0.f, 0.f, 0.f);
        if (gr < N) hv = *(const float4*)(h + (size_t)gr * 64 + kg * 4);
        float4 a4, b4;
        if (isl0) {
            a4 = make_float4(1.f, 1.f, 1.f, 1.f);
            b4 = make_float4(0.f, 0.f, 0.f, 0.f);
        } else {
            float4 s4 = *(const float4*)(bnsum + kg * 4);
            float4 q4 = *(const float4*)(bnsq + kg * 4);
            float4 g4 = *(const float4*)(bn_g + kg * 4);
            float4 t4 = *(const float4*)(bn_b + kg * 4);
            float mu;
            mu = s4.x * invN; a4.x = g4.x * rsqrtf(q4.x * invN - mu * mu + 1e-5f); b4.x = t4.x - mu * a4.x;
            mu = s4.y * invN; a4.y = g4.y * rsqrtf(q4.y * invN - mu * mu + 1e-5f); b4.y = t4.y - mu * a4.y;
            mu = s4.z * invN; a4.z = g4.z * rsqrtf(q4.z * invN - mu * mu + 1e-5f); b4.z = t4.z - mu * a4.z;
            mu = s4.w * invN; a4.w = g4.w * rsqrtf(q4.w * invN - mu * mu + 1e-5f); b4.w = t4.w - mu * a4.w;
        }
        half4v o4;
        o4[0] = (_Float16)(hv.x * a4.x + b4.x);
        o4[1] = (_Float16)(hv.y * a4.y + b4.y);
        o4[2] = (_Float16)(hv.z * a4.z + b4.z);
        o4[3] = (_Float16)(hv.w * a4.w + b4.w);
        *(half4v*)(&As[r * 72 + kg * 4]) = o4;
    }
    __syncthreads();

    int w = t >> 6, lane = t & 63;
    int y = w >> 2;
    const _Float16* Wm = Wt + (size_t)y * 16384;
    const float* bias  = y ? bdst : bsrc;
    _Float16* out      = y ? fdh : fsh;
    int n16 = lane & 15, qd = lane >> 4;
    int cw = (w & 3) * 64;
    f32x4 acc[4][4];
#pragma unroll
    for (int mt = 0; mt < 4; mt++)
#pragma unroll
        for (int nt = 0; nt < 4; nt++) acc[mt][nt] = (f32x4)(0.f);
    float bv[4];
#pragma unroll
    for (int nt = 0; nt < 4; nt++) bv[nt] = bias[cw + nt * 16 + n16];

#pragma unroll
    for (int kk = 0; kk < 2; kk++) {
        half8 af[4], bf[4];
#pragma unroll
        for (int mt = 0; mt < 4; mt++)
            af[mt] = *(const half8*)(&As[(mt * 16 + n16) * 72 + kk * 32 + qd * 8]);
#pragma unroll
        for (int nt = 0; nt < 4; nt++)
            bf[nt] = *(const half8*)(Wm + (size_t)(cw + nt * 16 + n16) * 64 + kk * 32 + qd * 8);
#pragma unroll
        for (int mt = 0; mt < 4; mt++)
#pragma unroll
            for (int nt = 0; nt < 4; nt++)
                acc[mt][nt] = __builtin_amdgcn_mfma_f32_16x16x32_f16(af[mt], bf[nt], acc[mt][nt], 0, 0, 0);
    }
#pragma unroll
    for (int mt = 0; mt < 4; mt++) {
#pragma unroll
        for (int i = 0; i < 4; i++) {
            int gr = row0 + mt * 16 + qd * 4 + i;
            if (gr < N) {
#pragma unroll
                for (int nt = 0; nt < 4; nt++)
                    out[(size_t)gr * 256 + cw + nt * 16 + n16] = (_Float16)(acc[mt][nt][i] + bv[nt]);
            }
        }
    }
}

// ---------------- fused GATv2 edge phase: wave per dst node ----------------

__global__ void __launch_bounds__(256) gat_kernel(
    const _Float16* __restrict__ fsh, const _Float16* __restrict__ fdh,
    const _Float16* __restrict__ att16,
    const int* __restrict__ row_ptr, const int* __restrict__ degv,
    const int* __restrict__ col_src,
    float* __restrict__ hmean, int N)
{
    int wid = (blockIdx.x << 2) + (threadIdx.x >> 6);
    if (wid >= N) return;
    int lane = threadIdx.x & 63;
    int e2 = lane >> 5;
    int d8 = lane & 31;
    int rs = row_ptr[wid];
    int deg = degv[wid];
    const int* cs = col_src + rs;

    half8 fdv = *(const half8*)(fdh + (size_t)wid * 256 + d8 * 8);
    half8 att = *(const half8*)(att16 + (d8 >> 3) * 64 + (d8 & 7) * 8);
    half8 k02;
#pragma unroll
    for (int j = 0; j < 8; j++) k02[j] = (_Float16)0.2f;

    float acc[8];
#pragma unroll
    for (int j = 0; j < 8; j++) acc[j] = 0.f;
    float l = 0.f;

    auto body = [&](half8 fv) {
        half8 x = fv + fdv;
        half8 lx = __builtin_elementwise_max(x, x * k02);
        float p = 0.f;
#ifdef USE_FDOT2
#pragma unroll
        for (int j = 0; j < 4; j++) {
            half2v a2 = { lx[2 * j], lx[2 * j + 1] };
            half2v b2 = { att[2 * j], att[2 * j + 1] };
            p = __builtin_amdgcn_fdot2(a2, b2, p, false);
        }
#else
#pragma unroll
        for (int j = 0; j < 8; j++) p = fmaf((float)lx[j], (float)att[j], p);
#endif
        p = dpp_sum8(p);
        float e = EX2(p);            // att pre-scaled by log2(e)
        l += e;
#pragma unroll
        for (int j = 0; j < 8; j++) acc[j] = fmaf(e, (float)fv[j], acc[j]);
    };

    int deg8 = deg & ~7;
    int4 nsv;
    if (deg8 > 0) nsv = *(const int4*)(cs + 4 * e2);   // 16B-aligned: padded CSR rows
    for (int i = 0; i < deg8; i += 8) {
        int4 sv = nsv;
        if (i + 8 < deg8) nsv = *(const int4*)(cs + i + 8 + 4 * e2);
        half8 f0 = *(const half8*)(fsh + (size_t)sv.x * 256 + d8 * 8);
        half8 f1 = *(const half8*)(fsh + (size_t)sv.y * 256 + d8 * 8);
        half8 f2 = *(const half8*)(fsh + (size_t)sv.z * 256 + d8 * 8);
        half8 f3 = *(const half8*)(fsh + (size_t)sv.w * 256 + d8 * 8);
        body(f0); body(f1); body(f2); body(f3);
    }
    for (int idx = deg8 + e2; idx < deg; idx += 2) {
        int s = cs[idx];
        half8 fv = *(const half8*)(fsh + (size_t)s * 256 + d8 * 8);
        body(fv);
    }

    l += __shfl_xor(l, 32);
#pragma unroll
    for (int j = 0; j < 8; j++) acc[j] += __shfl_xor(acc[j], 32);

    float inv = (l > 0.f) ? 0.25f / l : 0.f;
    float m[8];
#pragma unroll
    for (int j = 0; j < 8; j++) m[j] = fmaxf(acc[j] * inv, 0.f);
#pragma unroll
    for (int j = 0; j < 8; j++) {
        m[j] += __shfl_xor(m[j], 8);
        m[j] += __shfl_xor(m[j], 16);
    }
    if (lane < 8) {
        float4 o0 = make_float4(m[0], m[1], m[2], m[3]);
        float4 o1 = make_float4(m[4], m[5], m[6], m[7]);
        *(float4*)(hmean + (size_t)wid * 64 + d8 * 8) = o0;
        *(float4*)(hmean + (size_t)wid * 64 + d8 * 8 + 4) = o1;
    }
}

// ---------------- BN stats + graph segment sums ----------------

__global__ void __launch_bounds__(256) stats_kernel(
    const float* __restrict__ hmean, const int* __restrict__ gid,
    float* __restrict__ bnsum, float* __restrict__ bnsumsq,
    float* __restrict__ S, int N)
{
    __shared__ float bs[4][64], bq[4][64];
    int t = threadIdx.x, lane = t & 63, w = t >> 6;
    int wglobal = blockIdx.x * 4 + w;
    int chunk = (N + 511) >> 9;
    int n0 = wglobal * chunk;
    int n1 = min(n0 + chunk, N);
    float sum = 0.f, sq = 0.f, run = 0.f;
    int cur = -1;
    for (int n = n0; n < n1; n++) {
        float v = hmean[(size_t)n * 64 + lane];
        int g = gid[n];
        if (g != cur) {
            if (cur >= 0) atomicAdd(&S[cur * 64 + lane], run);
            run = 0.f;
            cur = g;
        }
        run += v;
        sum += v;
        sq = fmaf(v, v, sq);
    }
    if (cur >= 0) atomicAdd(&S[cur * 64 + lane], run);
    bs[w][lane] = sum;
    bq[w][lane] = sq;
    __syncthreads();
    if (w == 0) {
        float s2 = bs[0][lane] + bs[1][lane] + bs[2][lane] + bs[3][lane];
        float q2 = bq[0][lane] + bq[1][lane] + bq[2][lane] + bq[3][lane];
        atomicAdd(&bnsum[lane], s2);
        atomicAdd(&bnsumsq[lane], q2);
    }
}

// ---------------- pooled: per-graph MLP row (128 blocks) ----------------

__global__ void __launch_bounds__(256) pooled_a_kernel(
    const float* __restrict__ bnsum, const float* __restrict__ bnsumsq,
    const float* __restrict__ S, const int* __restrict__ cntg,
    const float* __restrict__ bn_g, const float* __restrict__ bn_b,
    const float* __restrict__ lpW, const float* __restrict__ lpb,
    float* __restrict__ q, float* __restrict__ qsum, float* __restrict__ qsq, int N)
{
    __shared__ float sv[64];
    __shared__ float partial[4][64];
    int g = blockIdx.x;
    int t = threadIdx.x;
    if (t < 64) {
        float mu = bnsum[t] / (float)N;
        float var = bnsumsq[t] / (float)N - mu * mu;
        float a = bn_g[t] / sqrtf(var + 1e-5f);
        float b = bn_b[t] - mu * a;
        sv[t] = a * S[g * 64 + t] + b * (float)cntg[g];
    }
    __syncthreads();
    int f = t & 63, kc = t >> 6;
    float acc = 0.f;
#pragma unroll
    for (int k = kc * 16; k < kc * 16 + 16; k++)
        acc = fmaf(sv[k], lpW[k * 64 + f], acc);
    partial[kc][f] = acc;
    __syncthreads();
    if (t < 64) {
        float v = partial[0][t] + partial[1][t] + partial[2][t] + partial[3][t] + lpb[t];
        v = fmaxf(v, 0.f);
        q[g * 64 + t] = v;
        atomicAdd(&qsum[t], v);
        atomicAdd(&qsq[t], v * v);
    }
}

// ------- head A: on-the-fly q-BN + cat GEMM (128 blocks) -------

__global__ void __launch_bounds__(256) head_gemm_kernel(
    const float* __restrict__ q, const float* __restrict__ qsum, const float* __restrict__ qsq,
    const float* __restrict__ lpg, const float* __restrict__ lpbt,
    const float* __restrict__ blW, const float* __restrict__ blb,
    float* __restrict__ hh, float* __restrict__ hsum, float* __restrict__ hsq)
{
    __shared__ float cat[192];
    __shared__ float partial[4][64];
    int g = blockIdx.x;
    int t = threadIdx.x;
    if (t < 192) {
        int ci = t >> 6, f = t & 63;
        float mu = qsum[ci * 64 + f] * (1.f / 128.f);
        float var = qsq[ci * 64 + f] * (1.f / 128.f) - mu * mu;
        float sc = lpg[ci * 64 + f] * rsqrtf(var + 1e-5f);
        cat[t] = (q[ci * 8192 + g * 64 + f] - mu) * sc + lpbt[ci * 64 + f];
    }
    __syncthreads();
    int f = t & 63, kc = t >> 6;
    float acc = 0.f;
#pragma unroll
    for (int k = kc * 48; k < kc * 48 + 48; k++)
        acc = fmaf(cat[k], blW[k * 64 + f], acc);
    partial[kc][f] = acc;
    __syncthreads();
    if (t < 64) {
        float v = partial[0][t] + partial[1][t] + partial[2][t] + partial[3][t] + blb[t];
        v = fmaxf(v, 0.f);
        hh[g * 64 + t] = v;
        atomicAdd(&hsum[t], v);
        atomicAdd(&hsq[t], v * v);
    }
}

// ---------------- head B ----------------

__global__ void __launch_bounds__(256) head_finish_kernel(
    const float* __restrict__ hh, const float* __restrict__ hsum, const float* __restrict__ hsq,
    const float* __restrict__ blg, const float* __restrict__ blbt,
    const float* __restrict__ llW, const float* __restrict__ llb,
    const float* __restrict__ llg, const float* __restrict__ llbt,
    float* __restrict__ out)
{
    __shared__ float hn[128][65];
    __shared__ float ph[128][12];
    __shared__ float mu[64], sc[64];
    __shared__ float mj[12], scj[12];
    __shared__ float sW[640];
    int t = threadIdx.x;
    if (t < 64) {
        float m = hsum[t] * (1.f / 128.f);
        float v = hsq[t] * (1.f / 128.f) - m * m;
        mu[t] = m;
        sc[t] = blg[t] / sqrtf(v + 1e-5f);
    }
    for (int i = t; i < 640; i += 256) sW[i] = llW[i];
    __syncthreads();
    for (int i = t; i < 8192; i += 256) {
        int g = i >> 6, ff = i & 63;
        float v = (hh[i] - mu[ff]) * sc[ff] + blbt[ff];
        out[1280 + i] = v;
        hn[g][ff] = v;
    }
    __syncthreads();
    for (int i = t; i < 1280; i += 256) {
        int g = i / 10, j = i - g * 10;
        float s = llb[j];
#pragma unroll 8
        for (int k = 0; k < 64; k++) s = fmaf(hn[g][k], sW[k * 10 + j], s);
        ph[g][j] = fmaxf(s, 0.f);
    }
    __syncthreads();
    if (t < 10) {
        float m = 0.f;
        for (int g = 0; g < 128; g++) m += ph[g][t];
        m *= (1.f / 128.f);
        float v = 0.f;
        for (int g = 0; g < 128; g++) { float d = ph[g][t] - m; v = fmaf(d, d, v); }
        v *= (1.f / 128.f);
        mj[t] = m;
        scj[t] = llg[t] / sqrtf(v + 1e-5f);
    }
    __syncthreads();
    if (t < 128) {
        float vals[10];
        float mx = -1e30f;
        for (int j = 0; j < 10; j++) {
            vals[j] = (ph[t][j] - mj[j]) * scj[j] + llbt[j];
            mx = fmaxf(mx, vals[j]);
        }
        float se = 0.f;
        for (int j = 0; j < 10; j++) se += __expf(vals[j] - mx);
        float lse = logf(se) + mx;
        for (int j = 0; j < 10; j++) out[t * 10 + j] = vals[j] - lse;
    }
}

// ---------------- launcher ----------------

extern "C" void kernel_launch(void* const* d_in, const int* in_sizes, int n_in,
                              void* d_out, int out_size, void* d_ws, size_t ws_size,
                              hipStream_t stream)
{
    const float* feat = (const float*)d_in[0];
    const float* Wsrc = (const float*)d_in[1];
    const float* bsrc = (const float*)d_in[2];
    const float* Wdst = (const float*)d_in[3];
    const float* bdst = (const float*)d_in[4];
    const float* attn = (const float*)d_in[5];
    const float* bn_g = (const float*)d_in[6];
    const float* bn_b = (const float*)d_in[7];
    const float* lpW  = (const float*)d_in[8];
    const float* lpb  = (const float*)d_in[9];
    const float* lpg  = (const float*)d_in[10];
    const float* lpbt = (const float*)d_in[11];
    const float* blW  = (const float*)d_in[12];
    const float* blb  = (const float*)d_in[13];
    const float* blg  = (const float*)d_in[14];
    const float* blbt = (const float*)d_in[15];
    const float* llW  = (const float*)d_in[16];
    const float* llb  = (const float*)d_in[17];
    const float* llg  = (const float*)d_in[18];
    const float* llbt = (const float*)d_in[19];
    const int* srcp = (const int*)d_in[20];
    const int* dstp = (const int*)d_in[21];
    const int* gidp = (const int*)d_in[22];
    float* out = (float*)d_out;

    int N = in_sizes[0] / 64;
    int E = in_sizes[20];
    int nb = (N + 1023) / 1024;

    // workspace (section sizes kept multiples of 4 floats -> 16B alignment)
    float* wsf = (float*)d_ws;
    _Float16* fsh = (_Float16*)wsf;                       // N*256 f16
    _Float16* fdh = (_Float16*)(wsf + (size_t)N * 128);   // N*256 f16
    float* hmean = wsf + (size_t)N * 256;            // N*64
    float* q     = hmean + (size_t)N * 64;           // 3*8192
    float* hh    = q + 24576;                        // 8192
    _Float16* Wt16  = (_Float16*)(hh + 8192);        // 6*16384 f16
    _Float16* att16 = (_Float16*)(hh + 8192 + 49152);// 768 f16
    float* zstart = hh + 8192 + 49152 + 384;
    float* bnsum = zstart;                           // 3*64
    float* bnsq  = bnsum + 192;                      // 3*64
    float* qsum  = bnsq + 192;                       // 3*64
    float* qsq   = qsum + 192;                       // 3*64
    float* hsum  = qsq + 192;                        // 64
    float* hsq   = hsum + 64;                        // 64
    float* S     = hsq + 64;                         // 3*8192
    int* deg     = (int*)(S + 24576);                // N
    int* gbase   = deg + N;                          // 4 (padded)
    int* zend    = gbase + 4;
    int* cntg    = zend;                             // 128
    int* gstart  = cntg + 128;                       // 128
    int* row_ptr = gstart + 128;                     // N
    int* col_src = row_ptr + N;                      // E + 3N + 64 (padded rows)
    int* pos     = col_src + E + 3 * N + 64;         // E

    size_t zbytes = (size_t)((char*)zend - (char*)zstart);
    hipMemsetAsync(zstart, 0, zbytes, stream);

    int hbBlocks = ((E > N ? E : N) + 255) / 256;
    hipLaunchKernelGGL(wcvt_hb_kernel, dim3(24 + hbBlocks), dim3(256), 0, stream,
                       Wsrc, Wdst, attn, Wt16, att16, dstp, deg, pos, gidp, gstart, N, E);
    hipLaunchKernelGGL(rowptr_kernel, dim3(nb), dim3(256), 0, stream,
                       deg, row_ptr, gbase, gstart, cntg, N);

    int gemmBlocks = (N + 63) / 64;
    int scatBlocks = (E + 511) / 512;
    for (int l = 0; l < 3; l++) {
        const float* hsrcp = (l == 0) ? feat : hmean;
        int sb = (l == 0) ? scatBlocks : 0;           // layer-1 gemm grid also scatters
        hipLaunchKernelGGL(gemm_kernel, dim3(gemmBlocks + sb), dim3(512), 0, stream,
                           hsrcp, bnsum + (l - 1) * 64, bnsq + (l - 1) * 64,
                           bn_g + (l - 1) * 64, bn_b + (l - 1) * 64,
                           (l == 0) ? 1 : 0, 1.f / (float)N,
                           Wt16 + (size_t)l * 32768, bsrc + l * 256, bdst + l * 256,
                           fsh, fdh, N, gemmBlocks,
                           srcp, dstp, row_ptr, pos, col_src, E);
        hipLaunchKernelGGL(gat_kernel, dim3((N + 3) / 4), dim3(256), 0, stream,
                           fsh, fdh, att16 + l * 256, row_ptr, deg, col_src, hmean, N);
        hipLaunchKernelGGL(stats_kernel, dim3(128), dim3(256), 0, stream,
                           hmean, gidp, bnsum + l * 64, bnsq + l * 64, S + l * 8192, N);
        hipLaunchKernelGGL(pooled_a_kernel, dim3(128), dim3(256), 0, stream,
                           bnsum + l * 64, bnsq + l * 64, S + l * 8192, cntg,
                           bn_g + l * 64, bn_b + l * 64,
                           lpW + (size_t)l * 4096, lpb + l * 64,
                           q + l * 8192, qsum + l * 64, qsq + l * 64, N);
    }
    hipLaunchKernelGGL(head_gemm_kernel, dim3(128), dim3(256), 0, stream,
                       q, qsum, qsq, lpg, lpbt, blW, blb, hh, hsum, hsq);
    hipLaunchKernelGGL(head_finish_kernel, dim3(1), dim3(256), 0, stream,
                       hh, hsum, hsq, blg, blbt, llW, llb, llg, llbt, out);
}

// Round 9
// 508.143 us; speedup vs baseline: 1.4053x; 1.0425x over previous
//
#include <hip/hip_runtime.h>
#include <cmath>

#define NH 4
#define NG 128

typedef _Float16 half8 __attribute__((ext_vector_type(8)));
typedef _Float16 half4v __attribute__((ext_vector_type(4)));
typedef _Float16 half2v __attribute__((ext_vector_type(2)));
typedef float f32x4 __attribute__((ext_vector_type(4)));

#if defined(__has_builtin)
# if __has_builtin(__builtin_amdgcn_fdot2)
#  define USE_FDOT2 1
# endif
# if __has_builtin(__builtin_amdgcn_update_dpp)
#  define USE_DPP 1
# endif
# if __has_builtin(__builtin_amdgcn_exp2f)
#  define EX2(x) __builtin_amdgcn_exp2f(x)
# endif
#endif
#ifndef EX2
# define EX2(x) exp2f(x)
#endif

__device__ inline float dpp_sum8(float p) {
#ifdef USE_DPP
    int pi = __builtin_bit_cast(int, p);
    int a = __builtin_amdgcn_update_dpp(0, pi, 0xB1, 0xF, 0xF, true);
    p += __builtin_bit_cast(float, a);
    pi = __builtin_bit_cast(int, p);
    a = __builtin_amdgcn_update_dpp(0, pi, 0x4E, 0xF, 0xF, true);
    p += __builtin_bit_cast(float, a);
    pi = __builtin_bit_cast(int, p);
    a = __builtin_amdgcn_update_dpp(0, pi, 0x141, 0xF, 0xF, true);
    p += __builtin_bit_cast(float, a);
    return p;
#else
    p += __shfl_xor(p, 1); p += __shfl_xor(p, 2); p += __shfl_xor(p, 4);
    return p;
#endif
}

// ------- fused: W->Wt[c][k] f16 (24 tile-blocks) + hist/pos + graph bounds -------

__global__ void __launch_bounds__(256) wcvt_hb_kernel(
    const float* __restrict__ Wsrc, const float* __restrict__ Wdst,
    const float* __restrict__ attn,
    _Float16* __restrict__ Wt, _Float16* __restrict__ att16,
    const int* __restrict__ dst, int* __restrict__ deg, int* __restrict__ pos,
    const int* __restrict__ gid, int* __restrict__ gstart, int N, int E)
{
    int t = threadIdx.x;
    if (blockIdx.x < 24) {
        __shared__ _Float16 lt[64 * 68];
        int b = blockIdx.x;
        int mat = b >> 2, ct = b & 3;
        int c0 = ct * 64;
        const float* W = ((mat & 1) ? Wdst : Wsrc) + (size_t)(mat >> 1) * 16384;
        _Float16* o = Wt + (size_t)mat * 16384;
#pragma unroll
        for (int i = 0; i < 16; i++) {
            int flat = i * 256 + t;
            int k = flat >> 6, c = flat & 63;
            lt[c * 68 + k] = (_Float16)W[k * 256 + c0 + c];
        }
        __syncthreads();
#pragma unroll
        for (int i = 0; i < 16; i++) {
            int flat = i * 256 + t;
            int c = flat >> 6, k = flat & 63;
            o[(size_t)(c0 + c) * 64 + k] = lt[c * 68 + k];
        }
        if (b == 0)
            for (int i = t; i < 3 * 256; i += 256)
                att16[i] = (_Float16)(attn[i] * 1.44269504f);   // fold log2(e)
        return;
    }
    int i = (blockIdx.x - 24) * 256 + t;
    if (i < E) pos[i] = atomicAdd(&deg[dst[i]], 1);
    if (i < N) {
        int a = gid[i];
        if (i == 0)
            for (int g = 0; g <= a; g++) gstart[g] = 0;
        int b2 = (i + 1 < N) ? gid[i + 1] : NG;
        for (int g = a + 1; g <= b2 && g < NG; g++) gstart[g] = i + 1;
    }
}

// single-dispatch row offsets, rows padded to multiples of 4 (for int4 col_src loads)
__global__ void __launch_bounds__(256) rowptr_kernel(const int* __restrict__ deg,
                                                     int* __restrict__ row_ptr,
                                                     int* __restrict__ gbase,
                                                     const int* __restrict__ gstart,
                                                     int* __restrict__ cntg, int N) {
    __shared__ int red[256];
    __shared__ int base_s;
    int t = threadIdx.x;
    int base = blockIdx.x * 1024 + t * 4;
    int dp[4];
    int s = 0;
#pragma unroll
    for (int j = 0; j < 4; j++) {
        int i = base + j;
        int d = (i < N) ? deg[i] : 0;
        dp[j] = (d + 3) & ~3;
        s += dp[j];
    }
    red[t] = s;
    __syncthreads();
    for (int off = 1; off < 256; off <<= 1) {
        int v = (t >= off) ? red[t - off] : 0;
        __syncthreads();
        red[t] += v;
        __syncthreads();
    }
    if (t == 255) base_s = atomicAdd(gbase, red[255]);
    __syncthreads();
    int excl = red[t] - s + base_s;
#pragma unroll
    for (int j = 0; j < 4; j++) {
        int i = base + j;
        if (i < N) row_ptr[i] = excl;
        excl += dp[j];
    }
    if (blockIdx.x == 0 && t < NG) {
        int s1 = (t == NG - 1) ? N : gstart[t + 1];
        cntg[t] = s1 - gstart[t];
    }
}

// ------- fused BN-affine + dual GEMM (f16 MFMA); extra roles: scatter, pooled MLP -------
// blocks [0, gemmBlocks): gemm; [gemmBlocks, +scatBlocks): scatter; rest: pooled graphs.

__global__ void __launch_bounds__(512) gemm_kernel(
    const float* __restrict__ h,
    const float* __restrict__ bnsum, const float* __restrict__ bnsq,
    const float* __restrict__ bn_g, const float* __restrict__ bn_b,
    int isl0, float invN,
    const _Float16* __restrict__ Wt,
    const float* __restrict__ bsrc, const float* __restrict__ bdst,
    _Float16* __restrict__ fsh, _Float16* __restrict__ fdh, int N,
    int gemmBlocks, int scatBlocks,
    const int* __restrict__ src, const int* __restrict__ dst,
    const int* __restrict__ row_ptr, const int* __restrict__ pos,
    int* __restrict__ col_src, int E,
    const float* __restrict__ S, const int* __restrict__ cntg,
    const float* __restrict__ plpW, const float* __restrict__ plpb,
    float* __restrict__ q, float* __restrict__ qsum, float* __restrict__ qsq)
{
    int t = threadIdx.x;
    if (blockIdx.x >= gemmBlocks) {
        int pb = blockIdx.x - gemmBlocks - scatBlocks;
        if (pb < 0) {                         // scatter role (atomic-free, pre-scaled)
            int e = (blockIdx.x - gemmBlocks) * 512 + t;
            if (e < E) {
                int d = dst[e];
                col_src[row_ptr[d] + pos[e]] = src[e] << 8;   // f16-element row offset
            }
            return;
        }
        // pooled role: graph pb, layer l-1 (uses the same stats as this gemm's BN)
        __shared__ float sv[64];
        __shared__ float partial[8][64];
        if (t < 64) {
            float mu = bnsum[t] * invN;
            float var = bnsq[t] * invN - mu * mu;
            float a = bn_g[t] * rsqrtf(var + 1e-5f);
            float b = bn_b[t] - mu * a;
            sv[t] = a * S[pb * 64 + t] + b * (float)cntg[pb];
        }
        __syncthreads();
        int f = t & 63, kc = t >> 6;
        float acc = 0.f;
#pragma unroll
        for (int k = kc * 8; k < kc * 8 + 8; k++)
            acc = fmaf(sv[k], plpW[k * 64 + f], acc);
        partial[kc][f] = acc;
        __syncthreads();
        if (t < 64) {
            float v = plpb[t];
#pragma unroll
            for (int j = 0; j < 8; j++) v += partial[j][t];
            v = fmaxf(v, 0.f);
            q[pb * 64 + t] = v;
            atomicAdd(&qsum[t], v);
            atomicAdd(&qsq[t], v * v);
        }
        return;
    }
    __shared__ _Float16 As[64 * 72];
    int row0 = blockIdx.x * 64;

#pragma unroll
    for (int i = 0; i < 2; i++) {
        int flat = i * 512 + t;
        int r = flat >> 4, kg = flat & 15;
        int gr = row0 + r;
        float4 hv = make_float4(0.f, 0.f, 0.f, 0.f);
        if (gr < N) hv = *(const float4*)(h + (size_t)gr * 64 + kg * 4);
        float4 a4, b4;
        if (isl0) {
            a4 = make_float4(1.f, 1.f, 1.f, 1.f);
            b4 = make_float4(0.f, 0.f, 0.f, 0.f);
        } else {
            float4 s4 = *(const float4*)(bnsum + kg * 4);
            float4 q4 = *(const float4*)(bnsq + kg * 4);
            float4 g4 = *(const float4*)(bn_g + kg * 4);
            float4 t4 = *(const float4*)(bn_b + kg * 4);
            float mu;
            mu = s4.x * invN; a4.x = g4.x * rsqrtf(q4.x * invN - mu * mu + 1e-5f); b4.x = t4.x - mu * a4.x;
            mu = s4.y * invN; a4.y = g4.y * rsqrtf(q4.y * invN - mu * mu + 1e-5f); b4.y = t4.y - mu * a4.y;
            mu = s4.z * invN; a4.z = g4.z * rsqrtf(q4.z * invN - mu * mu + 1e-5f); b4.z = t4.z - mu * a4.z;
            mu = s4.w * invN; a4.w = g4.w * rsqrtf(q4.w * invN - mu * mu + 1e-5f); b4.w = t4.w - mu * a4.w;
        }
        half4v o4;
        o4[0] = (_Float16)(hv.x * a4.x + b4.x);
        o4[1] = (_Float16)(hv.y * a4.y + b4.y);
        o4[2] = (_Float16)(hv.z * a4.z + b4.z);
        o4[3] = (_Float16)(hv.w * a4.w + b4.w);
        *(half4v*)(&As[r * 72 + kg * 4]) = o4;
    }
    __syncthreads();

    int w = t >> 6, lane = t & 63;
    int y = w >> 2;
    const _Float16* Wm = Wt + (size_t)y * 16384;
    const float* bias  = y ? bdst : bsrc;
    _Float16* out      = y ? fdh : fsh;
    int n16 = lane & 15, qd = lane >> 4;
    int cw = (w & 3) * 64;
    f32x4 acc[4][4];
#pragma unroll
    for (int mt = 0; mt < 4; mt++)
#pragma unroll
        for (int nt = 0; nt < 4; nt++) acc[mt][nt] = (f32x4)(0.f);
    float bv[4];
#pragma unroll
    for (int nt = 0; nt < 4; nt++) bv[nt] = bias[cw + nt * 16 + n16];

#pragma unroll
    for (int kk = 0; kk < 2; kk++) {
        half8 af[4], bf[4];
#pragma unroll
        for (int mt = 0; mt < 4; mt++)
            af[mt] = *(const half8*)(&As[(mt * 16 + n16) * 72 + kk * 32 + qd * 8]);
#pragma unroll
        for (int nt = 0; nt < 4; nt++)
            bf[nt] = *(const half8*)(Wm + (size_t)(cw + nt * 16 + n16) * 64 + kk * 32 + qd * 8);
#pragma unroll
        for (int mt = 0; mt < 4; mt++)
#pragma unroll
            for (int nt = 0; nt < 4; nt++)
                acc[mt][nt] = __builtin_amdgcn_mfma_f32_16x16x32_f16(af[mt], bf[nt], acc[mt][nt], 0, 0, 0);
    }
#pragma unroll
    for (int mt = 0; mt < 4; mt++) {
#pragma unroll
        for (int i = 0; i < 4; i++) {
            int gr = row0 + mt * 16 + qd * 4 + i;
            if (gr < N) {
#pragma unroll
                for (int nt = 0; nt < 4; nt++)
                    out[(size_t)gr * 256 + cw + nt * 16 + n16] = (_Float16)(acc[mt][nt][i] + bv[nt]);
            }
        }
    }
}

// ---------------- fused GATv2 edge phase: wave per dst node ----------------
// lane = e2*32 + d8. int4 index loads (pre-scaled row offsets), 2-deep feature staging.

__global__ void __launch_bounds__(256) gat_kernel(
    const _Float16* __restrict__ fsh, const _Float16* __restrict__ fdh,
    const _Float16* __restrict__ att16,
    const int* __restrict__ row_ptr, const int* __restrict__ degv,
    const int* __restrict__ col_src,
    float* __restrict__ hmean, int N)
{
    int wid = (blockIdx.x << 2) + (threadIdx.x >> 6);
    if (wid >= N) return;
    int lane = threadIdx.x & 63;
    int e2 = lane >> 5;
    int d8 = lane & 31;
    int rs = row_ptr[wid];
    int deg = degv[wid];
    const int* cs = col_src + rs;
    const _Float16* fsb = fsh + d8 * 8;

    half8 fdv = *(const half8*)(fdh + (size_t)wid * 256 + d8 * 8);
    half8 att = *(const half8*)(att16 + (d8 >> 3) * 64 + (d8 & 7) * 8);
    half8 k02;
#pragma unroll
    for (int j = 0; j < 8; j++) k02[j] = (_Float16)0.2f;

    float acc[8];
#pragma unroll
    for (int j = 0; j < 8; j++) acc[j] = 0.f;
    float l = 0.f;

    auto body = [&](half8 fv) {
        half8 x = fv + fdv;
        half8 lx = __builtin_elementwise_max(x, x * k02);
        float p = 0.f;
#ifdef USE_FDOT2
#pragma unroll
        for (int j = 0; j < 4; j++) {
            half2v a2 = { lx[2 * j], lx[2 * j + 1] };
            half2v b2 = { att[2 * j], att[2 * j + 1] };
            p = __builtin_amdgcn_fdot2(a2, b2, p, false);
        }
#else
#pragma unroll
        for (int j = 0; j < 8; j++) p = fmaf((float)lx[j], (float)att[j], p);
#endif
        p = dpp_sum8(p);
        float e = EX2(p);            // att pre-scaled by log2(e)
        l += e;
#pragma unroll
        for (int j = 0; j < 8; j++) acc[j] = fmaf(e, (float)fv[j], acc[j]);
    };

    int deg8 = deg & ~7;
    int4 nsv;
    if (deg8 > 0) nsv = *(const int4*)(cs + 4 * e2);   // 16B-aligned (padded CSR)
    for (int i = 0; i < deg8; i += 8) {
        int4 sv = nsv;
        if (i + 8 < deg8) nsv = *(const int4*)(cs + i + 8 + 4 * e2);
        // 2-deep staging: at most 2 feature rows in flight -> low VGPR pressure
        half8 f0 = *(const half8*)(fsb + (size_t)(unsigned)sv.x);
        half8 f1 = *(const half8*)(fsb + (size_t)(unsigned)sv.y);
        body(f0);
        half8 f2 = *(const half8*)(fsb + (size_t)(unsigned)sv.z);
        body(f1);
        half8 f3 = *(const half8*)(fsb + (size_t)(unsigned)sv.w);
        body(f2);
        body(f3);
    }
    for (int idx = deg8 + e2; idx < deg; idx += 2) {
        int s = cs[idx];
        half8 fv = *(const half8*)(fsb + (size_t)(unsigned)s);
        body(fv);
    }

    l += __shfl_xor(l, 32);
#pragma unroll
    for (int j = 0; j < 8; j++) acc[j] += __shfl_xor(acc[j], 32);

    float inv = (l > 0.f) ? 0.25f / l : 0.f;
    float m[8];
#pragma unroll
    for (int j = 0; j < 8; j++) m[j] = fmaxf(acc[j] * inv, 0.f);
#pragma unroll
    for (int j = 0; j < 8; j++) {
        m[j] += __shfl_xor(m[j], 8);
        m[j] += __shfl_xor(m[j], 16);
    }
    if (lane < 8) {
        float4 o0 = make_float4(m[0], m[1], m[2], m[3]);
        float4 o1 = make_float4(m[4], m[5], m[6], m[7]);
        *(float4*)(hmean + (size_t)wid * 64 + d8 * 8) = o0;
        *(float4*)(hmean + (size_t)wid * 64 + d8 * 8 + 4) = o1;
    }
}

// ---------------- BN stats + graph segment sums ----------------

__global__ void __launch_bounds__(256) stats_kernel(
    const float* __restrict__ hmean, const int* __restrict__ gid,
    float* __restrict__ bnsum, float* __restrict__ bnsumsq,
    float* __restrict__ S, int N)
{
    __shared__ float bs[4][64], bq[4][64];
    int t = threadIdx.x, lane = t & 63, w = t >> 6;
    int wglobal = blockIdx.x * 4 + w;
    int chunk = (N + 511) >> 9;
    int n0 = wglobal * chunk;
    int n1 = min(n0 + chunk, N);
    float sum = 0.f, sq = 0.f, run = 0.f;
    int cur = -1;
    for (int n = n0; n < n1; n++) {
        float v = hmean[(size_t)n * 64 + lane];
        int g = gid[n];
        if (g != cur) {
            if (cur >= 0) atomicAdd(&S[cur * 64 + lane], run);
            run = 0.f;
            cur = g;
        }
        run += v;
        sum += v;
        sq = fmaf(v, v, sq);
    }
    if (cur >= 0) atomicAdd(&S[cur * 64 + lane], run);
    bs[w][lane] = sum;
    bq[w][lane] = sq;
    __syncthreads();
    if (w == 0) {
        float s2 = bs[0][lane] + bs[1][lane] + bs[2][lane] + bs[3][lane];
        float q2 = bq[0][lane] + bq[1][lane] + bq[2][lane] + bq[3][lane];
        atomicAdd(&bnsum[lane], s2);
        atomicAdd(&bnsumsq[lane], q2);
    }
}

// ---------------- pooled (standalone, used for layer 2 only) ----------------

__global__ void __launch_bounds__(256) pooled_a_kernel(
    const float* __restrict__ bnsum, const float* __restrict__ bnsumsq,
    const float* __restrict__ S, const int* __restrict__ cntg,
    const float* __restrict__ bn_g, const float* __restrict__ bn_b,
    const float* __restrict__ lpW, const float* __restrict__ lpb,
    float* __restrict__ q, float* __restrict__ qsum, float* __restrict__ qsq, int N)
{
    __shared__ float sv[64];
    __shared__ float partial[4][64];
    int g = blockIdx.x;
    int t = threadIdx.x;
    if (t < 64) {
        float mu = bnsum[t] / (float)N;
        float var = bnsumsq[t] / (float)N - mu * mu;
        float a = bn_g[t] / sqrtf(var + 1e-5f);
        float b = bn_b[t] - mu * a;
        sv[t] = a * S[g * 64 + t] + b * (float)cntg[g];
    }
    __syncthreads();
    int f = t & 63, kc = t >> 6;
    float acc = 0.f;
#pragma unroll
    for (int k = kc * 16; k < kc * 16 + 16; k++)
        acc = fmaf(sv[k], lpW[k * 64 + f], acc);
    partial[kc][f] = acc;
    __syncthreads();
    if (t < 64) {
        float v = partial[0][t] + partial[1][t] + partial[2][t] + partial[3][t] + lpb[t];
        v = fmaxf(v, 0.f);
        q[g * 64 + t] = v;
        atomicAdd(&qsum[t], v);
        atomicAdd(&qsq[t], v * v);
    }
}

// ------- head A: on-the-fly q-BN + cat GEMM (128 blocks) -------

__global__ void __launch_bounds__(256) head_gemm_kernel(
    const float* __restrict__ q, const float* __restrict__ qsum, const float* __restrict__ qsq,
    const float* __restrict__ lpg, const float* __restrict__ lpbt,
    const float* __restrict__ blW, const float* __restrict__ blb,
    float* __restrict__ hh, float* __restrict__ hsum, float* __restrict__ hsq)
{
    __shared__ float cat[192];
    __shared__ float partial[4][64];
    int g = blockIdx.x;
    int t = threadIdx.x;
    if (t < 192) {
        int ci = t >> 6, f = t & 63;
        float mu = qsum[ci * 64 + f] * (1.f / 128.f);
        float var = qsq[ci * 64 + f] * (1.f / 128.f) - mu * mu;
        float sc = lpg[ci * 64 + f] * rsqrtf(var + 1e-5f);
        cat[t] = (q[ci * 8192 + g * 64 + f] - mu) * sc + lpbt[ci * 64 + f];
    }
    __syncthreads();
    int f = t & 63, kc = t >> 6;
    float acc = 0.f;
#pragma unroll
    for (int k = kc * 48; k < kc * 48 + 48; k++)
        acc = fmaf(cat[k], blW[k * 64 + f], acc);
    partial[kc][f] = acc;
    __syncthreads();
    if (t < 64) {
        float v = partial[0][t] + partial[1][t] + partial[2][t] + partial[3][t] + blb[t];
        v = fmaxf(v, 0.f);
        hh[g * 64 + t] = v;
        atomicAdd(&hsum[t], v);
        atomicAdd(&hsq[t], v * v);
    }
}

// ---------------- head B ----------------

__global__ void __launch_bounds__(256) head_finish_kernel(
    const float* __restrict__ hh, const float* __restrict__ hsum, const float* __restrict__ hsq,
    const float* __restrict__ blg, const float* __restrict__ blbt,
    const float* __restrict__ llW, const float* __restrict__ llb,
    const float* __restrict__ llg, const float* __restrict__ llbt,
    float* __restrict__ out)
{
    __shared__ float hn[128][65];
    __shared__ float ph[128][12];
    __shared__ float mu[64], sc[64];
    __shared__ float mj[12], scj[12];
    __shared__ float sW[640];
    int t = threadIdx.x;
    if (t < 64) {
        float m = hsum[t] * (1.f / 128.f);
        float v = hsq[t] * (1.f / 128.f) - m * m;
        mu[t] = m;
        sc[t] = blg[t] / sqrtf(v + 1e-5f);
    }
    for (int i = t; i < 640; i += 256) sW[i] = llW[i];
    __syncthreads();
    for (int i = t; i < 8192; i += 256) {
        int g = i >> 6, ff = i & 63;
        float v = (hh[i] - mu[ff]) * sc[ff] + blbt[ff];
        out[1280 + i] = v;
        hn[g][ff] = v;
    }
    __syncthreads();
    for (int i = t; i < 1280; i += 256) {
        int g = i / 10, j = i - g * 10;
        float s = llb[j];
#pragma unroll 8
        for (int k = 0; k < 64; k++) s = fmaf(hn[g][k], sW[k * 10 + j], s);
        ph[g][j] = fmaxf(s, 0.f);
    }
    __syncthreads();
    if (t < 10) {
        float m = 0.f;
        for (int g = 0; g < 128; g++) m += ph[g][t];
        m *= (1.f / 128.f);
        float v = 0.f;
        for (int g = 0; g < 128; g++) { float d = ph[g][t] - m; v = fmaf(d, d, v); }
        v *= (1.f / 128.f);
        mj[t] = m;
        scj[t] = llg[t] / sqrtf(v + 1e-5f);
    }
    __syncthreads();
    if (t < 128) {
        float vals[10];
        float mx = -1e30f;
        for (int j = 0; j < 10; j++) {
            vals[j] = (ph[t][j] - mj[j]) * scj[j] + llbt[j];
            mx = fmaxf(mx, vals[j]);
        }
        float se = 0.f;
        for (int j = 0; j < 10; j++) se += __expf(vals[j] - mx);
        float lse = logf(se) + mx;
        for (int j = 0; j < 10; j++) out[t * 10 + j] = vals[j] - lse;
    }
}

// ---------------- launcher ----------------

extern "C" void kernel_launch(void* const* d_in, const int* in_sizes, int n_in,
                              void* d_out, int out_size, void* d_ws, size_t ws_size,
                              hipStream_t stream)
{
    const float* feat = (const float*)d_in[0];
    const float* Wsrc = (const float*)d_in[1];
    const float* bsrc = (const float*)d_in[2];
    const float* Wdst = (const float*)d_in[3];
    const float* bdst = (const float*)d_in[4];
    const float* attn = (const float*)d_in[5];
    const float* bn_g = (const float*)d_in[6];
    const float* bn_b = (const float*)d_in[7];
    const float* lpW  = (const float*)d_in[8];
    const float* lpb  = (const float*)d_in[9];
    const float* lpg  = (const float*)d_in[10];
    const float* lpbt = (const float*)d_in[11];
    const float* blW  = (const float*)d_in[12];
    const float* blb  = (const float*)d_in[13];
    const float* blg  = (const float*)d_in[14];
    const float* blbt = (const float*)d_in[15];
    const float* llW  = (const float*)d_in[16];
    const float* llb  = (const float*)d_in[17];
    const float* llg  = (const float*)d_in[18];
    const float* llbt = (const float*)d_in[19];
    const int* srcp = (const int*)d_in[20];
    const int* dstp = (const int*)d_in[21];
    const int* gidp = (const int*)d_in[22];
    float* out = (float*)d_out;

    int N = in_sizes[0] / 64;
    int E = in_sizes[20];
    int nb = (N + 1023) / 1024;

    // workspace
    float* wsf = (float*)d_ws;
    _Float16* fsh = (_Float16*)wsf;                       // N*256 f16
    _Float16* fdh = (_Float16*)(wsf + (size_t)N * 128);   // N*256 f16
    float* hmean = wsf + (size_t)N * 256;            // N*64
    float* q     = hmean + (size_t)N * 64;           // 3*8192
    float* hh    = q + 24576;                        // 8192
    _Float16* Wt16  = (_Float16*)(hh + 8192);        // 6*16384 f16
    _Float16* att16 = (_Float16*)(hh + 8192 + 49152);// 768 f16
    float* zstart = hh + 8192 + 49152 + 384;
    float* bnsum = zstart;                           // 3*64
    float* bnsq  = bnsum + 192;                      // 3*64
    float* qsum  = bnsq + 192;                       // 3*64
    float* qsq   = qsum + 192;                       // 3*64
    float* hsum  = qsq + 192;                        // 64
    float* hsq   = hsum + 64;                        // 64
    float* S     = hsq + 64;                         // 3*8192
    int* deg     = (int*)(S + 24576);                // N
    int* gbase   = deg + N;                          // 4 (padded)
    int* zend    = gbase + 4;
    int* cntg    = zend;                             // 128
    int* gstart  = cntg + 128;                       // 128
    int* row_ptr = gstart + 128;                     // N
    int* col_src = row_ptr + N;                      // E + 3N + 64 (padded rows)
    int* pos     = col_src + E + 3 * N + 64;         // E

    size_t zbytes = (size_t)((char*)zend - (char*)zstart);
    hipMemsetAsync(zstart, 0, zbytes, stream);

    int hbBlocks = ((E > N ? E : N) + 255) / 256;
    hipLaunchKernelGGL(wcvt_hb_kernel, dim3(24 + hbBlocks), dim3(256), 0, stream,
                       Wsrc, Wdst, attn, Wt16, att16, dstp, deg, pos, gidp, gstart, N, E);
    hipLaunchKernelGGL(rowptr_kernel, dim3(nb), dim3(256), 0, stream,
                       deg, row_ptr, gbase, gstart, cntg, N);

    int gemmBlocks = (N + 63) / 64;
    int scatBlocks = (E + 511) / 512;
    for (int l = 0; l < 3; l++) {
        const float* hsrcp = (l == 0) ? feat : hmean;
        int sb = (l == 0) ? scatBlocks : 0;   // layer-0 gemm grid also scatters
        int pb = (l >= 1) ? NG : 0;           // layer>=1 gemm grid also runs pooled(l-1)
        hipLaunchKernelGGL(gemm_kernel, dim3(gemmBlocks + sb + pb), dim3(512), 0, stream,
                           hsrcp, bnsum + (l - 1) * 64, bnsq + (l - 1) * 64,
                           bn_g + (l - 1) * 64, bn_b + (l - 1) * 64,
                           (l == 0) ? 1 : 0, 1.f / (float)N,
                           Wt16 + (size_t)l * 32768, bsrc + l * 256, bdst + l * 256,
                           fsh, fdh, N, gemmBlocks, sb,
                           srcp, dstp, row_ptr, pos, col_src, E,
                           S + (l - 1) * 8192, cntg,
                           lpW + (size_t)(l - 1) * 4096, lpb + (l - 1) * 64,
                           q + (l - 1) * 8192, qsum + (l - 1) * 64, qsq + (l - 1) * 64);
        hipLaunchKernelGGL(gat_kernel, dim3((N + 3) / 4), dim3(256), 0, stream,
                           fsh, fdh, att16 + l * 256, row_ptr, deg, col_src, hmean, N);
        hipLaunchKernelGGL(stats_kernel, dim3(128), dim3(256), 0, stream,
                           hmean, gidp, bnsum + l * 64, bnsq + l * 64, S + l * 8192, N);
    }
    hipLaunchKernelGGL(pooled_a_kernel, dim3(128), dim3(256), 0, stream,
                       bnsum + 2 * 64, bnsq + 2 * 64, S + 2 * 8192, cntg,
                       bn_g + 2 * 64, bn_b + 2 * 64,
                       lpW + (size_t)2 * 4096, lpb + 2 * 64,
                       q + 2 * 8192, qsum + 2 * 64, qsq + 2 * 64, N);
    hipLaunchKernelGGL(head_gemm_kernel, dim3(128), dim3(256), 0, stream,
                       q, qsum, qsq, lpg, lpbt, blW, blb, hh, hsum, hsq);
    hipLaunchKernelGGL(head_finish_kernel, dim3(1), dim3(256), 0, stream,
                       hh, hsum, hsq, blg, blbt, llW, llb, llg, llbt, out);
}